// Round 4
// baseline (38319.122 us; speedup 1.0000x reference)
//
#include <hip/hip_runtime.h>
#include <hip/hip_bf16.h>

typedef unsigned long long u64;

#define MBYTE (1ull << 20)

// ---------------- workspace layout (bytes) ----------------
static const size_t OFF_A64   = 0;                    // 1024^2 f64 (8MB)
static const size_t OFF_VT    = 8*MBYTE;              // 1024^2 f32 (4MB) reflectors transposed
static const size_t OFF_TAU   = 12*MBYTE;             // 1024 f64
static const size_t OFF_D64   = 12*MBYTE +  8192;
static const size_t OFF_E64   = 12*MBYTE + 16384;
static const size_t OFF_XB    = 12*MBYTE + 24576;     // barrier flags (256 u32)
static const size_t OFF_Y2B   = 12*MBYTE + 32768;     // y2 pong
static const size_t OFF_Y1B   = 12*MBYTE + 40960;     // y1 pong
static const size_t OFF_XA    = 12*MBYTE + 49152;     // diag publication (1024 f64)
static const size_t OFF_Y1A   = 12*MBYTE + 57344;     // y1 ping
static const size_t OFF_Y2A   = 12*MBYTE + 65536;     // y2 ping
static const size_t OFF_QA    = 13*MBYTE;             // 4MB f32 (D&C Q, later U)
static const size_t OFF_QB    = 17*MBYTE;             // 4MB f32
static const size_t OFF_SHAT  = 21*MBYTE;             // 4MB f32
static const size_t OFF_WC    = 25*MBYTE;             // 8MB f32; during D&C holds batched merge scratch
static const size_t OFF_M1    = 33*MBYTE;             // 8MB f32
static const size_t OFF_T8    = 33*MBYTE;             // 2MB f32 (reuses M1, dead by then)
static const size_t OFF_ALPHA = 35*MBYTE + 512*1024;  // float[8] (dead region)
static const size_t OFF_ADJ   = 41*MBYTE;             // 16MB f32
static const size_t OFF_OADJ  = 17*MBYTE;             // 16MB f32 (reuses QB/SHAT/WC, dead)
static const size_t OFF_CBUF  = 0;                    // 16MB f32 (reuses A64/VT/QA, dead)

// batched D&C scratch inside the (dead-during-D&C) WC region
static const size_t SCD_STRIDE = 9216;   // doubles per merge
static const size_t SCI_STRIDE = 6144;   // ints per merge
static const size_t OFF_SCDB  = OFF_WC;                       // 32*9216*8 = 2359296
static const size_t OFF_SCIB  = OFF_WC + 2359296;             // 32*6144*4 = 786432
static const size_t OFF_KNB   = OFF_WC + 2359296 + 786432;    // 32*8 ints
static const size_t OFF_KNDB  = OFF_WC + 2359296 + 786432 + 2048; // 32*4 dbl

// ================= tridiagonalization (ssytd2-faithful, lower, f64) =================
// PERSISTENT kernel, 256 blocks x 256 threads (4 waves), STATIC row ownership:
//   wave w of block b owns row w*256+b. A64 rows block-private -> L2-resident, no
//   flush in the loop. Cross-block data (y1/y2/diag, ~24KB/step) moves via relaxed
//   agent-scope atomics (bypass L2); steps separated by a contention-free FLAG
//   barrier (per-block release store + wave-0 spin over 256 flags, 4/lane).
//   y1/y2 are staged into LDS at step start (one latency round trip, overlapped
//   with the norm pass) instead of serialized atomic loads inside the P pass.
//   Phase A passes fused (v into P; w-correction into x-update) -- per-element
//   arithmetic and order identical to the round-3 passing kernel.

__global__ void kCopyA(const float* __restrict__ A, double* __restrict__ A64) {
  int gid = blockIdx.x*256 + threadIdx.x;
  if (gid < 1024*1024) A64[gid] = (double)A[gid];
}

__device__ __forceinline__ double agLoadD(const double* p) {
  return __hip_atomic_load(p, __ATOMIC_RELAXED, __HIP_MEMORY_SCOPE_AGENT);
}
__device__ __forceinline__ void agStoreD(double* p, double v) {
  __hip_atomic_store(p, v, __ATOMIC_RELAXED, __HIP_MEMORY_SCOPE_AGENT);
}

#define TD_NBLK 256

__global__ __launch_bounds__(256) void kTriDiag(
    double* __restrict__ A64,
    double* __restrict__ y1A, double* __restrict__ y1B,
    double* __restrict__ y2A, double* __restrict__ y2B,
    double* __restrict__ diagP, unsigned* __restrict__ flags,
    double* __restrict__ tauv, double* __restrict__ e64, double* __restrict__ d64,
    float* __restrict__ Vt) {
  __shared__ double xL[1024], vL[1024], wL[1024], y1L[1024], y2L[1024];
  __shared__ double red[4];
  __shared__ double sS[4];
  int tid = threadIdx.x;
  int bid = blockIdx.x;
  bool w0 = (bid == 0);
  int lane = tid & 63, wave = tid >> 6;   // 4 waves
  int myRow = wave*TD_NBLK + bid;         // bijective 0..1023

  for (int i = 0; i <= 1023; ++i) {
    const double* y1in = (((i-1)&1) != 0) ? y1B : y1A;   // only used for i>=1
    const double* y2in = (((i-1)&1) != 0) ? y2B : y2A;
    double* y1out = ((i&1) != 0) ? y1B : y1A;
    double* y2out = ((i&1) != 0) ? y2B : y2A;

    if (i == 0) {
      for (int c = tid; c < 1024; c += 256) { vL[c] = 0.0; wL[c] = 0.0; }
      for (int c = 1 + tid; c < 1024; c += 256) xL[c] = A64[(u64)c*1024];
      if (w0 && tid == 0) d64[0] = A64[0];
      __syncthreads();
    } else {
      int j = i - 1;                       // reflector being finalized
      // ---- stage y into LDS (published step i-1; ordered by barrier) ----
      double a1[4], a2[4];
      #pragma unroll
      for (int k = 0; k < 4; ++k) {
        a1[k] = agLoadD(&y1in[tid + 256*k]);
        a2[k] = agLoadD(&y2in[tid + 256*k]);
      }
      double dg = 0.0;
      if (w0 && tid == 0) dg = agLoadD(&diagP[i]);
      // ---- norm^2 pass (LDS only, overlaps the staging loads) ----
      double acc = 0.0;
      for (int c = i + 1 + tid; c < 1024; c += 256) { double v = xL[c]; acc += v*v; }
      for (int off = 32; off > 0; off >>= 1) acc += __shfl_xor(acc, off, 64);
      if (lane == 0) red[wave] = acc;
      #pragma unroll
      for (int k = 0; k < 4; ++k) { y1L[tid + 256*k] = a1[k]; y2L[tid + 256*k] = a2[k]; }
      __syncthreads();                                   // S1
      if (tid == 0) {
        double xn2 = red[0] + red[1] + red[2] + red[3];
        double alpha = xL[i];
        double tv, sc;
        if (xn2 == 0.0) { tv = 0.0; if (w0) e64[j] = alpha; sc = 0.0; }
        else {
          double beta = (alpha >= 0.0) ? -sqrt(alpha*alpha + xn2) : sqrt(alpha*alpha + xn2);
          tv = (beta - alpha)/beta;
          if (w0) e64[j] = beta;
          sc = 1.0/(alpha - beta);
        }
        if (w0) tauv[j] = tv;
        sS[0] = sc; sS[1] = tv;
        vL[i] = 1.0;
        if (w0) Vt[(u64)j*1024 + i] = 1.0f;
      }
      __syncthreads();                                   // S2
      {
        // fused v-scale + P pass (same per-element values/order as separate passes)
        double sc = sS[0], tv = sS[1];
        double acc2 = 0.0;
        for (int r = i + tid; r < 1024; r += 256) {
          double v;
          if (r == i) v = 1.0;
          else {
            v = xL[r]*sc;
            vL[r] = v;
            if (w0) Vt[(u64)j*1024 + r] = (float)v;
          }
          double P = tv*(y1L[r] + sc*y2L[r]);
          wL[r] = P;
          acc2 += P*v;
        }
        for (int off = 32; off > 0; off >>= 1) acc2 += __shfl_xor(acc2, off, 64);
        if (lane == 0) red[wave] = acc2;
      }
      __syncthreads();                                   // S3
      if (tid == 0) {
        double coef = 0.5*sS[1]*(red[0] + red[1] + red[2] + red[3]);
        double wi = wL[i] - coef;    // == corrected wL[i] (vL[i]=1)
        sS[2] = coef; sS[3] = wi;
        if (w0) d64[i] = dg - 2.0*wi;
      }
      __syncthreads();                                   // S4
      {
        // fused w-correction + x-update
        double coef = sS[2], wi = sS[3];
        for (int r = i + tid; r < 1024; r += 256) {
          double wcr = wL[r] - coef*vL[r];
          wL[r] = wcr;
          if (r > i) xL[r] = y1L[r] - vL[r]*wi - wcr;
        }
      }
      __syncthreads();                                   // S5
    }
    // ---- Phase B: rank-2 apply to OWN row fused with y1/y2 = A'*x ----
    if (i <= 1022) {
      int r = myRow;
      if (r >= i + 1) {
        double vr = vL[r], wr = wL[r];
        double* Arow = A64 + (u64)r*1024;
        double acc = 0.0, y1v = 0.0;
        int c = i + 1 + lane;
        // 4-way unrolled (4 loads in flight); accumulation order preserved
        for (; c + 192 < 1024; c += 256) {
          double A0 = Arow[c], A1 = Arow[c+64], A2 = Arow[c+128], A3 = Arow[c+192];
          double w0_ = wL[c], w1_ = wL[c+64], w2_ = wL[c+128], w3_ = wL[c+192];
          double v0_ = vL[c], v1_ = vL[c+64], v2_ = vL[c+128], v3_ = vL[c+192];
          double x0_ = xL[c], x1_ = xL[c+64], x2_ = xL[c+128], x3_ = xL[c+192];
          double b0 = A0 - vr*w0_ - wr*v0_;
          double b1 = A1 - vr*w1_ - wr*v1_;
          double b2 = A2 - vr*w2_ - wr*v2_;
          double b3 = A3 - vr*w3_ - wr*v3_;
          Arow[c] = b0; Arow[c+64] = b1; Arow[c+128] = b2; Arow[c+192] = b3;
          if (c == r)     agStoreD(&diagP[r], b0);
          if (c+64 == r)  agStoreD(&diagP[r], b1);
          if (c+128 == r) agStoreD(&diagP[r], b2);
          if (c+192 == r) agStoreD(&diagP[r], b3);
          if (c == i + 1) y1v = b0; else acc += b0*x0_;
          acc += b1*x1_;
          acc += b2*x2_;
          acc += b3*x3_;
        }
        for (; c < 1024; c += 64) {
          double a = Arow[c] - vr*wL[c] - wr*vL[c];
          Arow[c] = a;
          if (c == r) agStoreD(&diagP[r], a);
          if (c == i + 1) y1v = a; else acc += a*xL[c];
        }
        for (int off = 32; off > 0; off >>= 1) acc += __shfl_down(acc, off, 64);
        if (lane == 0) { agStoreD(&y1out[r], y1v); agStoreD(&y2out[r], acc); }
      }
      // all waves' Phase B stores drained before arrival (compiler waitcnt @ barrier)
      __syncthreads();                                   // S6
      // ---- contention-free flag barrier (release store + acquire spin) ----
      unsigned tgt = (unsigned)(i + 1);
      if (tid == 0)
        __hip_atomic_store(&flags[bid], tgt, __ATOMIC_RELEASE, __HIP_MEMORY_SCOPE_AGENT);
      if (tid < 64) {
        for (;;) {
          unsigned m0 = __hip_atomic_load(&flags[tid      ], __ATOMIC_ACQUIRE, __HIP_MEMORY_SCOPE_AGENT);
          unsigned m1 = __hip_atomic_load(&flags[tid +  64], __ATOMIC_ACQUIRE, __HIP_MEMORY_SCOPE_AGENT);
          unsigned m2 = __hip_atomic_load(&flags[tid + 128], __ATOMIC_ACQUIRE, __HIP_MEMORY_SCOPE_AGENT);
          unsigned m3 = __hip_atomic_load(&flags[tid + 192], __ATOMIC_ACQUIRE, __HIP_MEMORY_SCOPE_AGENT);
          unsigned ma = (m0 < m1) ? m0 : m1;
          unsigned mb = (m2 < m3) ? m2 : m3;
          unsigned mn = (ma < mb) ? ma : mb;
          if (__all(mn >= tgt)) break;
          __builtin_amdgcn_s_sleep(2);
        }
      }
      __syncthreads();                                   // S7
    }
  }
  // folded kCuts (block-0 thread-0 local data only)
  if (w0 && tid == 0) {
    for (int c = 16; c < 1024; c += 16) {
      double ae = fabs(e64[c-1]);
      d64[c-1] -= ae;
      d64[c]   -= ae;
    }
  }
}

// ================= ssteqr (leaves, n=16, COMPZ='I') =================

__device__ void slartg_(double f, double g, double* cs, double* sn, double* r) {
  if (g == 0.0) { *cs = 1.0; *sn = 0.0; *r = f; }
  else if (f == 0.0) { *cs = 0.0; *sn = (g >= 0.0) ? 1.0 : -1.0; *r = fabs(g); }
  else {
    double d = sqrt(f*f + g*g);
    *cs = fabs(f)/d;
    *r = (f >= 0.0) ? d : -d;
    *sn = g / (*r);
  }
}

__device__ void slaev2_(double a, double b, double c, double* rt1, double* rt2,
                        double* cs1, double* sn1) {
  double sm = a + c, df = a - c, adf = fabs(df), tb = b + b, ab = fabs(tb);
  double acmx, acmn;
  if (fabs(a) > fabs(c)) { acmx = a; acmn = c; } else { acmx = c; acmn = a; }
  double rt;
  if (adf > ab) rt = adf*sqrt(1.0 + (ab/adf)*(ab/adf));
  else if (adf < ab) rt = ab*sqrt(1.0 + (adf/ab)*(adf/ab));
  else rt = ab*sqrt(2.0);
  int sgn1;
  if (sm < 0.0) { *rt1 = 0.5*(sm - rt); sgn1 = -1; *rt2 = (acmx / *rt1)*acmn - (b / *rt1)*b; }
  else if (sm > 0.0) { *rt1 = 0.5*(sm + rt); sgn1 = 1; *rt2 = (acmx / *rt1)*acmn - (b / *rt1)*b; }
  else { *rt1 = 0.5*rt; *rt2 = -0.5*rt; sgn1 = 1; }
  int sgn2; double cs;
  if (df >= 0.0) { cs = df + rt; sgn2 = 1; } else { cs = df - rt; sgn2 = -1; }
  double acs = fabs(cs);
  if (acs > ab) { double ct = -tb/cs; *sn1 = 1.0/sqrt(1.0 + ct*ct); *cs1 = ct*(*sn1); }
  else {
    if (ab == 0.0) { *cs1 = 1.0; *sn1 = 0.0; }
    else { double tn = -cs/tb; *cs1 = 1.0/sqrt(1.0 + tn*tn); *sn1 = tn*(*cs1); }
  }
  if (sgn1 == sgn2) { double tn = *cs1; *cs1 = -(*sn1); *sn1 = tn; }
}

__device__ void steqr16_(double* d, double* e, double* z, double* wc, double* ws_) {
  const int n = 16;
  const double eps = 5.9604644775390625e-08;
  const double eps2 = eps*eps;
  const double safmin = 1.1754943508222875e-38;
  int jtot = 0; const int nmaxit = n*30;
  int l1 = 0;
  for (int outer = 0; outer < 200; ++outer) {
    if (l1 > n-1) break;
    if (l1 > 0) e[l1-1] = 0.0;
    int m = l1;
    for (; m <= n-2; ++m) {
      double tst = fabs(e[m]);
      if (tst == 0.0) break;
      if (tst <= (sqrt(fabs(d[m]))*sqrt(fabs(d[m+1])))*eps) { e[m] = 0.0; break; }
    }
    int l = l1, lend = m;
    l1 = m + 1;
    if (lend == l) continue;
    if (fabs(d[lend]) < fabs(d[l])) { int t = l; l = lend; lend = t; }
    if (lend > l) {
      for (int it = 0; it < 800; ++it) {
        int mm = lend;
        if (l != lend) {
          for (mm = l; mm <= lend-1; ++mm) {
            double tst = e[mm]*e[mm];
            if (tst <= eps2*fabs(d[mm])*fabs(d[mm+1]) + safmin) break;
          }
        }
        if (mm < lend) e[mm] = 0.0;
        double p = d[l];
        if (mm == l) { d[l] = p; ++l; if (l <= lend) continue; break; }
        if (mm == l+1) {
          double rt1, rt2, c2, s2;
          slaev2_(d[l], e[l], d[l+1], &rt1, &rt2, &c2, &s2);
          for (int r = 0; r < n; ++r) {
            double t = z[r*16 + l + 1];
            z[r*16 + l + 1] = c2*t - s2*z[r*16 + l];
            z[r*16 + l]     = s2*t + c2*z[r*16 + l];
          }
          d[l] = rt1; d[l+1] = rt2; e[l] = 0.0;
          l += 2; if (l <= lend) continue; break;
        }
        if (jtot == nmaxit) break;
        ++jtot;
        double g = (d[l+1] - p)/(2.0*e[l]);
        double r_ = sqrt(g*g + 1.0);
        g = d[mm] - p + e[l]/(g + ((g >= 0.0) ? r_ : -r_));
        double s = 1.0, c = 1.0;
        p = 0.0;
        for (int i = mm-1; i >= l; --i) {
          double f = s*e[i], b = c*e[i];
          double cs, sn, rr;
          slartg_(g, f, &cs, &sn, &rr);
          c = cs; s = sn;
          if (i != mm-1) e[i+1] = rr;
          g = d[i+1] - p;
          rr = (d[i] - g)*s + 2.0*c*b;
          p = s*rr;
          d[i+1] = g + p;
          g = c*rr - b;
          wc[i] = c; ws_[i] = -s;
        }
        for (int jj = mm-1; jj >= l; --jj) {
          double cs = wc[jj], sn = ws_[jj];
          for (int r = 0; r < n; ++r) {
            double t = z[r*16 + jj + 1];
            z[r*16 + jj + 1] = cs*t - sn*z[r*16 + jj];
            z[r*16 + jj]     = sn*t + cs*z[r*16 + jj];
          }
        }
        d[l] -= p;
        e[l] = g;
      }
    } else {
      for (int it = 0; it < 800; ++it) {
        int mm = lend;
        if (l != lend) {
          for (mm = l; mm >= lend+1; --mm) {
            double tst = e[mm-1]*e[mm-1];
            if (tst <= eps2*fabs(d[mm])*fabs(d[mm-1]) + safmin) break;
          }
        }
        if (mm > lend) e[mm-1] = 0.0;
        double p = d[l];
        if (mm == l) { d[l] = p; --l; if (l >= lend) continue; break; }
        if (mm == l-1) {
          double rt1, rt2, c2, s2;
          slaev2_(d[l-1], e[l-1], d[l], &rt1, &rt2, &c2, &s2);
          for (int r = 0; r < n; ++r) {
            double t = z[r*16 + l];
            z[r*16 + l]     = c2*t - s2*z[r*16 + l - 1];
            z[r*16 + l - 1] = s2*t + c2*z[r*16 + l - 1];
          }
          d[l-1] = rt1; d[l] = rt2; e[l-1] = 0.0;
          l -= 2; if (l >= lend) continue; break;
        }
        if (jtot == nmaxit) break;
        ++jtot;
        double g = (d[l-1] - p)/(2.0*e[l-1]);
        double r_ = sqrt(g*g + 1.0);
        g = d[mm] - p + e[l-1]/(g + ((g >= 0.0) ? r_ : -r_));
        double s = 1.0, c = 1.0;
        p = 0.0;
        for (int i = mm; i <= l-1; ++i) {
          double f = s*e[i], b = c*e[i];
          double cs, sn, rr;
          slartg_(g, f, &cs, &sn, &rr);
          c = cs; s = sn;
          if (i != mm) e[i-1] = rr;
          g = d[i] - p;
          rr = (d[i+1] - g)*s + 2.0*c*b;
          p = s*rr;
          d[i] = g + p;
          g = c*rr - b;
          wc[i] = c; ws_[i] = s;
        }
        for (int jj = mm; jj <= l-1; ++jj) {
          double cs = wc[jj], sn = ws_[jj];
          for (int r = 0; r < n; ++r) {
            double t = z[r*16 + jj + 1];
            z[r*16 + jj + 1] = cs*t - sn*z[r*16 + jj];
            z[r*16 + jj]     = sn*t + cs*z[r*16 + jj];
          }
        }
        d[l] -= p;
        e[l-1] = g;
      }
    }
  }
  for (int ii = 1; ii <= n-1; ++ii) {
    int i = ii - 1, k = i;
    double p = d[i];
    for (int j = ii; j <= n-1; ++j) if (d[j] < p) { k = j; p = d[j]; }
    if (k != i) {
      d[k] = d[i]; d[i] = p;
      for (int r = 0; r < n; ++r) { double t = z[r*16 + i]; z[r*16 + i] = z[r*16 + k]; z[r*16 + k] = t; }
    }
  }
}

__global__ void kLeaf(double* d64, const double* e64, float* Qa) {
  __shared__ double dd[16], ed[16], zd[256], wk1[16], wk2[16];
  int leaf = blockIdx.x, lo = leaf*16, tid = threadIdx.x;
  for (int idx = tid; idx < 256; idx += 64) zd[idx] = ((idx/16) == (idx%16)) ? 1.0 : 0.0;
  if (tid < 16) { dd[tid] = d64[lo + tid]; ed[tid] = (tid < 15) ? e64[lo + tid] : 0.0; }
  __syncthreads();
  if (tid == 0) steqr16_(dd, ed, zd, wk1, wk2);
  __syncthreads();
  for (int idx = tid; idx < 256; idx += 64) {
    int r = idx/16, c = idx%16;
    Qa[(u64)(lo + r)*1024 + lo + c] = (float)zd[idx];
  }
  if (tid < 16) d64[lo + tid] = dd[tid];
}

// ================= batched D&C merge =================
// scd per-merge (doubles): 1024 dl | 2048 wm | 3072 mu | 4096 zh | 7168 dval
// sci per-merge (ints):    0 permsec | 1024 deflc | 4096 rootpos | 5120 dpos

__global__ __launch_bounds__(1024) void kDeflateB(float* __restrict__ Qa,
      const double* __restrict__ d64, const double* __restrict__ e64,
      double* scdB, int* sciB, int* knB, double* kndB, int bs) {
  __shared__ double zL[1024], dlocL[1024], redD[1024];
  __shared__ double rcL[1024], rsL[1024];
  __shared__ int sIdxL[1024], rpqL[1024];
  __shared__ double sSc[4];
  __shared__ int sKn[4];
  int mg = blockIdx.x;
  int n1 = bs, n = 2*bs, lo = mg*n;
  double* scd = scdB + (u64)mg*SCD_STRIDE;
  int*    sci = sciB + (u64)mg*SCI_STRIDE;
  int* kn = knB + mg*8;
  double* knd = kndB + mg*4;
  int tid = threadIdx.x;
  if (tid == 0) sSc[0] = e64[lo + n1 - 1];
  __syncthreads();
  double rho_in = sSc[0];
  const double invs2 = 0.70710678118654752440;
  if (tid < n) {
    int row = (tid < n1) ? (lo + n1 - 1) : (lo + n1);
    double s = (rho_in < 0.0 && tid >= n1) ? -invs2 : invs2;
    zL[tid] = (double)Qa[(u64)row*1024 + lo + tid] * s;
    dlocL[tid] = d64[lo + tid];
  }
  __syncthreads();
  if (tid < n) {
    int pos; double key = dlocL[tid];
    if (tid < n1) {
      int loB = 0, hiB = n - n1;
      while (loB < hiB) { int mid = (loB+hiB)>>1; if (dlocL[n1+mid] < key) loB = mid+1; else hiB = mid; }
      pos = tid + loB;
    } else {
      int loA = 0, hiA = n1;
      while (loA < hiA) { int mid = (loA+hiA)>>1; if (dlocL[mid] <= key) loA = mid+1; else hiA = mid; }
      pos = (tid - n1) + loA;
    }
    sIdxL[pos] = tid;
  }
  redD[tid] = (tid < n) ? fabs(zL[tid]) : 0.0;
  __syncthreads();
  for (int s = 512; s > 0; s >>= 1) { if (tid < s) redD[tid] = fmax(redD[tid], redD[tid+s]); __syncthreads(); }
  if (tid == 0) sSc[1] = redD[0];
  __syncthreads();
  redD[tid] = (tid < n) ? fabs(dlocL[tid]) : 0.0;
  __syncthreads();
  for (int s = 512; s > 0; s >>= 1) { if (tid < s) redD[tid] = fmax(redD[tid], redD[tid+s]); __syncthreads(); }
  if (tid == 0) {
    double zmax = sSc[1], dmax = redD[0];
    double rho = fabs(2.0*rho_in);
    double tol = 8.0*5.9604644775390625e-8*fmax(dmax, zmax);
    double* dlG = scd + 1024;
    double* wmG = scd + 2048;
    double* dvalG = scd + 7168;
    int* permG = sci;
    int* deflG = sci + 1024;
    int K = 0, nrot = 0, nd = 0; double sw2 = 0.0;
    if (rho*zmax <= tol) {
      for (int pos = 0; pos < n; ++pos) { int c = sIdxL[pos]; deflG[nd] = c; dvalG[nd] = dlocL[c]; nd++; }
    } else {
      int pj = -1, jpos = 0;
      for (; jpos < n; ++jpos) {
        int nj = sIdxL[jpos];
        if (rho*fabs(zL[nj]) <= tol) { deflG[nd] = nj; dvalG[nd] = dlocL[nj]; nd++; }
        else { pj = nj; break; }
      }
      for (++jpos; jpos < n; ++jpos) {
        int nj = sIdxL[jpos];
        if (rho*fabs(zL[nj]) <= tol) { deflG[nd] = nj; dvalG[nd] = dlocL[nj]; nd++; continue; }
        double s_ = zL[pj], c_ = zL[nj];
        double tu = sqrt(c_*c_ + s_*s_);
        double tdif = dlocL[nj] - dlocL[pj];
        c_ /= tu; s_ = -s_/tu;
        if (fabs(tdif*c_*s_) <= tol) {
          zL[nj] = tu; zL[pj] = 0.0;
          rpqL[nrot] = (pj << 16) | nj; rcL[nrot] = c_; rsL[nrot] = s_; nrot++;
          double t1 = dlocL[pj]*c_*c_ + dlocL[nj]*s_*s_;
          dlocL[nj] = dlocL[pj]*s_*s_ + dlocL[nj]*c_*c_;
          dlocL[pj] = t1;
          deflG[nd] = pj; dvalG[nd] = t1; nd++;
          pj = nj;
        } else {
          permG[K] = pj; dlG[K] = dlocL[pj]; wmG[K] = zL[pj]; sw2 += zL[pj]*zL[pj]; K++;
          pj = nj;
        }
      }
      permG[K] = pj; dlG[K] = dlocL[pj]; wmG[K] = zL[pj]; sw2 += zL[pj]*zL[pj]; K++;
    }
    sKn[1] = nrot;
    kn[0] = K; kn[1] = nrot; kn[2] = nd;
    knd[0] = rho; knd[1] = sw2;
  }
  __syncthreads();
  int nrot = sKn[1];
  if (tid < n && nrot > 0) {
    u64 row = (u64)(lo + tid)*1024;
    for (int t = 0; t < nrot; ++t) {
      int pq = rpqL[t];
      int p = lo + (pq >> 16), q = lo + (pq & 0xffff);
      double c = rcL[t], s = rsL[t];
      double x = (double)Qa[row + p], y = (double)Qa[row + q];
      Qa[row + p] = (float)(c*x + s*y);
      Qa[row + q] = (float)(c*y - s*x);
    }
  }
}

__global__ __launch_bounds__(256) void kSecularB(double* scdB, const int* knB, const double* kndB) {
  __shared__ double dlS[1024], wmS[1024];
  int mg = blockIdx.y;
  double* scd = scdB + (u64)mg*SCD_STRIDE;
  const int* kn = knB + mg*8;
  const double* knd = kndB + mg*4;
  int K = kn[0];
  int tid = threadIdx.x;
  for (int j = tid; j < K; j += 256) { dlS[j] = scd[1024 + j]; wmS[j] = scd[2048 + j]; }
  __syncthreads();
  int wave = tid >> 6, lane = tid & 63;
  int i = blockIdx.x*4 + wave;
  if (i >= K) return;
  double rho = knd[0], sw2 = knd[1];
  double di = dlS[i];
  double hi = (i < K-1) ? (dlS[i+1] - di) : (rho*sw2*(1.0 + 1e-12) + 1e-300);
  double lo_ = 0.0;
  for (int it = 0; it < 100; ++it) {
    double mid = 0.5*(lo_ + hi);
    double g = 0.0;
    for (int j = lane; j < K; j += 64) { double w = wmS[j]; g += w*w/((dlS[j] - di) - mid); }
    for (int off = 32; off > 0; off >>= 1) g += __shfl_xor(g, off);
    g = 1.0 + rho*g;
    if (g < 0.0) lo_ = mid; else hi = mid;
  }
  scd[3072 + i] = 0.5*(lo_ + hi);
}

__global__ void kZhatB(double* scdB, const int* knB) {
  int mg = blockIdx.y;
  double* scd = scdB + (u64)mg*SCD_STRIDE;
  int K = (knB + mg*8)[0];
  int j = blockIdx.x*64 + threadIdx.x;
  if (j >= K) return;
  const double* dl = scd + 1024;
  const double* wm = scd + 2048;
  const double* mu = scd + 3072;
  double dj = dl[j];
  double prod = mu[j];
  for (int i2 = 0; i2 < K; ++i2) {
    if (i2 == j) continue;
    double dd = dl[i2] - dj;
    prod *= (dd + mu[i2]) / dd;
  }
  prod = fabs(prod);
  scd[4096 + j] = (wm[j] >= 0.0) ? sqrt(prod) : -sqrt(prod);
}

__global__ __launch_bounds__(1024) void kSortPermB(double* scdB, int* sciB, const int* knB,
                                                   double* d64, int bs) {
  __shared__ double sv[1024];
  __shared__ int si[1024];
  int mg = blockIdx.x;
  int n = 2*bs, lo = mg*n;
  double* scd = scdB + (u64)mg*SCD_STRIDE;
  int* sci = sciB + (u64)mg*SCI_STRIDE;
  int K = (knB + mg*8)[0];
  int tid = threadIdx.x;
  const double* dl = scd + 1024;
  const double* mu = scd + 3072;
  const double* dval = scd + 7168;
  double v;
  if (tid < K) v = dl[tid] + mu[tid];
  else if (tid < n) v = dval[tid - K];
  else v = 1e300;
  sv[tid] = v; si[tid] = tid;
  __syncthreads();
  for (int k = 2; k <= 1024; k <<= 1) {
    for (int j = k >> 1; j > 0; j >>= 1) {
      int ixj = tid ^ j;
      if (ixj > tid) {
        bool up = ((tid & k) == 0);
        double a = sv[tid], b = sv[ixj];
        int ia = si[tid], ib = si[ixj];
        bool agtb = (a > b) || (a == b && ia > ib);
        if (up ? agtb : !agtb) { sv[tid] = b; sv[ixj] = a; si[tid] = ib; si[ixj] = ia; }
      }
      __syncthreads();
    }
  }
  if (tid < n) {
    int s = si[tid];
    if (s < K) sci[4096 + s] = tid; else sci[5120 + s - K] = tid;
    d64[lo + tid] = sv[tid];
  }
}

__global__ void kSvecNormB(float* __restrict__ Shat, const double* scdB, const int* knB, int bs) {
  int mg = blockIdx.y;
  int n = 2*bs, lo = mg*n;
  const double* scd = scdB + (u64)mg*SCD_STRIDE;
  int K = (knB + mg*8)[0];
  int i = blockIdx.x;
  if (i >= K) return;
  const double* dl = scd + 1024;
  const double* mu = scd + 3072;
  const double* zh = scd + 4096;
  __shared__ double red[256];
  int tid = threadIdx.x;
  double di = dl[i], m = mu[i];
  double acc = 0.0;
  for (int j = tid; j < K; j += 256) {
    double v = zh[j]/((dl[j] - di) - m);
    acc += v*v;
  }
  red[tid] = acc; __syncthreads();
  for (int s = 128; s > 0; s >>= 1) { if (tid < s) red[tid] += red[tid+s]; __syncthreads(); }
  double inv = 1.0/sqrt(red[0]);
  for (int j = tid; j < K; j += 256) {
    double v = zh[j]/((dl[j] - di) - m);
    Shat[(u64)j*1024 + lo + i] = (float)(v*inv);
  }
}

__global__ void kGatherB(const float* Qa, float* Qb, const int* sciB, const int* knB, int bs) {
  int mg = blockIdx.y;
  int n = 2*bs, lo = mg*n;
  const int* sci = sciB + (u64)mg*SCI_STRIDE;
  int K = (knB + mg*8)[0];
  int gid = blockIdx.x*256 + threadIdx.x;
  if (gid >= n*n) return;
  int p = gid % n, r = gid / n;
  int src = (p < K) ? sci[p] : sci[1024 + p - K];
  Qb[(u64)(lo + r)*1024 + p] = Qa[(u64)(lo + r)*1024 + lo + src];
}

__global__ void kGemmMergeB(const float* __restrict__ Qb, const float* __restrict__ Shat,
                            float* __restrict__ Qa, const int* sciB, const int* knB, int bs) {
  __shared__ float As[16][17], Bs[16][17];
  int mg = blockIdx.z;
  int n = 2*bs, lo = mg*n;
  const int* sci = sciB + (u64)mg*SCI_STRIDE;
  int K = (knB + mg*8)[0];
  int tx = threadIdx.x, ty = threadIdx.y;
  int r0 = blockIdx.y*16, c0 = blockIdx.x*16;
  const int* rootpos = sci + 4096;
  float acc = 0.f;
  for (int k0 = 0; k0 < K; k0 += 16) {
    As[ty][tx] = (k0 + tx < K) ? Qb[(u64)(lo + r0 + ty)*1024 + k0 + tx] : 0.f;
    Bs[ty][tx] = (k0 + ty < K && c0 + tx < K) ? Shat[(u64)(k0 + ty)*1024 + lo + c0 + tx] : 0.f;
    __syncthreads();
    #pragma unroll
    for (int kk = 0; kk < 16; ++kk) acc += As[ty][kk]*Bs[kk][tx];
    __syncthreads();
  }
  int i = c0 + tx;
  if (i < K) Qa[(u64)(lo + r0 + ty)*1024 + lo + rootpos[i]] = acc;
}

__global__ void kScatterDeflB(const float* Qb, float* Qa, const int* sciB, const int* knB, int bs) {
  int mg = blockIdx.y;
  int n = 2*bs, lo = mg*n;
  const int* sci = sciB + (u64)mg*SCI_STRIDE;
  const int* kn = knB + mg*8;
  int gid = blockIdx.x*256 + threadIdx.x;
  if (gid >= n*n) return;
  int p = gid % n, r = gid / n;
  int K = kn[0], nd = kn[2];
  if (p < K || p - K >= nd) return;
  Qa[(u64)(lo + r)*1024 + lo + sci[5120 + p - K]] = Qb[(u64)(lo + r)*1024 + p];
}

// ================= back-transform =================
// PAIRED reflectors: Z <- H_b H_a Z per iteration using
//   Z' = Z - ta*va*da - tb*vb*(db - ta*s*da),  s = vb^T va
// halves the serial chain (511 pairs + 1) and the Z traffic.
__global__ void kBackx(float* __restrict__ Qa, const float* __restrict__ Vt,
                       const double* __restrict__ tau) {
  __shared__ double redA[256], redB[256], redS[16];
  __shared__ double fA[16], fB[16];
  int tid = threadIdx.x;
  int cix = tid & 15, strip = tid >> 4;
  int col = blockIdx.x*16 + cix;
  for (int a = 1022; a >= 2; a -= 2) {
    int b = a - 1;
    double ta = tau[a], tb = tau[b];
    const float* va_row = Vt + (u64)a*1024;
    const float* vb_row = Vt + (u64)b*1024;
    double pda = 0.0, pdb = 0.0, ps = 0.0;
    for (int r = a + strip; r < 1024; r += 16) {
      double zb = (double)Qa[(u64)r*1024 + col];
      double va = (r > a) ? (double)va_row[r] : 0.0;   // Vt[a][a] is unwritten
      double vb = (double)vb_row[r];                   // Vt[b][a] == 1
      pda += va*zb; pdb += vb*zb;
      if (cix == 0) ps += va*vb;
    }
    redA[tid] = pda; redB[tid] = pdb;
    if (cix == 0) redS[strip] = ps;
    __syncthreads();
    if (tid < 16) {
      double da = 0.0, db = 0.0, s = 0.0;
      for (int u = 0; u < 16; ++u) {
        da += redA[u*16 + tid];
        db += redB[u*16 + tid];
        s  += redS[u];
      }
      fA[tid] = ta*da;
      fB[tid] = tb*(db - ta*s*da);
    }
    __syncthreads();
    double fa = fA[cix], fb = fB[cix];
    for (int r = a + strip; r < 1024; r += 16) {
      double va = (r > a) ? (double)va_row[r] : 0.0;
      double vb = (double)vb_row[r];
      Qa[(u64)r*1024 + col] -= (float)(fa*va + fb*vb);
    }
    __syncthreads();
  }
  // leftover reflector 0
  {
    double t0 = tau[0];
    const float* v_row = Vt;
    double pd = 0.0;
    for (int r = 1 + strip; r < 1024; r += 16)
      pd += (double)v_row[r] * (double)Qa[(u64)r*1024 + col];
    redA[tid] = pd;
    __syncthreads();
    if (tid < 16) {
      double d = 0.0;
      for (int u = 0; u < 16; ++u) d += redA[u*16 + tid];
      fA[tid] = t0*d;
    }
    __syncthreads();
    double f = fA[cix];
    for (int r = 1 + strip; r < 1024; r += 16)
      Qa[(u64)r*1024 + col] -= (float)(f * (double)v_row[r]);
  }
}

// ================= downstream math =================

// 128x128 tile, 8x8 micro-tile, BK=8, float4 everywhere
template<int TA, int TB>
__global__ __launch_bounds__(256) void gemm_f32(const float* __restrict__ A,
    const float* __restrict__ B, float* __restrict__ C,
    int M, int N, int Kd, int lda, int ldb, int ldc) {
  __shared__ float As[8][132];
  __shared__ float Bs[8][132];
  int tid = threadIdx.x;
  int bi = blockIdx.y*128, bj = blockIdx.x*128;
  int tx = tid & 15, ty = tid >> 4;
  float acc[8][8];
  #pragma unroll
  for (int x = 0; x < 8; ++x)
    #pragma unroll
    for (int y = 0; y < 8; ++y) acc[x][y] = 0.f;
  for (int k0 = 0; k0 < Kd; k0 += 8) {
    if (TA == 0) {
      int row = tid >> 1, kc = (tid & 1)*4;
      float4 v = *(const float4*)&A[(u64)(bi + row)*lda + k0 + kc];
      As[kc+0][row] = v.x; As[kc+1][row] = v.y; As[kc+2][row] = v.z; As[kc+3][row] = v.w;
    } else {
      int kk = tid >> 5, col = (tid & 31)*4;
      float4 v = *(const float4*)&A[(u64)(k0 + kk)*lda + bi + col];
      *(float4*)&As[kk][col] = v;
    }
    if (TB == 0) {
      int kk = tid >> 5, col = (tid & 31)*4;
      float4 v = *(const float4*)&B[(u64)(k0 + kk)*ldb + bj + col];
      *(float4*)&Bs[kk][col] = v;
    } else {
      int row = tid >> 1, kc = (tid & 1)*4;
      float4 v = *(const float4*)&B[(u64)(bj + row)*ldb + k0 + kc];
      Bs[kc+0][row] = v.x; Bs[kc+1][row] = v.y; Bs[kc+2][row] = v.z; Bs[kc+3][row] = v.w;
    }
    __syncthreads();
    #pragma unroll
    for (int kk = 0; kk < 8; ++kk) {
      float a[8], b[8];
      *(float4*)&a[0] = *(float4*)&As[kk][ty*8];
      *(float4*)&a[4] = *(float4*)&As[kk][ty*8 + 4];
      *(float4*)&b[0] = *(float4*)&Bs[kk][tx*8];
      *(float4*)&b[4] = *(float4*)&Bs[kk][tx*8 + 4];
      #pragma unroll
      for (int x = 0; x < 8; ++x)
        #pragma unroll
        for (int y = 0; y < 8; ++y) acc[x][y] += a[x]*b[y];
    }
    __syncthreads();
  }
  #pragma unroll
  for (int x = 0; x < 8; ++x) {
    float* Crow = &C[(u64)(bi + ty*8 + x)*ldc + bj + tx*8];
    *(float4*)&Crow[0] = make_float4(acc[x][0], acc[x][1], acc[x][2], acc[x][3]);
    *(float4*)&Crow[4] = make_float4(acc[x][4], acc[x][5], acc[x][6], acc[x][7]);
  }
}

__global__ void kWc(const float* W, float* Wc) {
  int gid = blockIdx.x*256 + threadIdx.x;
  if (gid >= 2048*1024) return;
  int i = gid >> 10, k = gid & 1023;
  Wc[gid] = W[(u64)i*2048 + k] + W[(u64)i*2048 + 1024 + k];
}

__global__ void kAbsDiag(float* adj) {
  int gid = blockIdx.x*256 + threadIdx.x;
  if (gid >= 2048*2048) return;
  int i = gid >> 11, j = gid & 2047;
  float v = fabsf(adj[gid]);
  adj[gid] = (i == j) ? 1.0f : v;
}

__global__ void kTk(const float* __restrict__ adj, const float* __restrict__ masks,
                    const float* __restrict__ Us, float* __restrict__ t8) {
  int k = blockIdx.y;
  int i = blockIdx.x*16 + (threadIdx.x >> 4);
  int r = threadIdx.x & 15;
  const float* arow = adj + (u64)i*2048;
  const float* mrow = masks + ((u64)k*2048 + i)*2048;
  const float* uk = Us + (u64)k*2048*16 + r;
  float acc = 0.f;
  for (int j = 0; j < 2048; ++j) acc += arow[j]*mrow[j]*uk[(u64)j*16];
  t8[((u64)k*2048 + i)*16 + r] = acc;
}

__global__ void kAlpha(const float* alphas, float* alpha) {
  if (threadIdx.x == 0 && blockIdx.x == 0) {
    float m = alphas[0];
    for (int k = 1; k < 8; ++k) m = fmaxf(m, alphas[k]);
    float e[8]; float s = 0.f;
    for (int k = 0; k < 8; ++k) { e[k] = expf(alphas[k] - m); s += e[k]; }
    for (int k = 0; k < 8; ++k) alpha[k] = e[k]/s;
  }
}

__global__ void kOutAdj(const float* __restrict__ adj, const float* __restrict__ masks,
                        const float* __restrict__ Vs, const float* __restrict__ t8,
                        const float* __restrict__ alpha, float* __restrict__ oadj,
                        float* __restrict__ out0) {
  __shared__ float tS[8][16][16];
  __shared__ float vS[8][16][16];
  int j0 = blockIdx.x*16, i0 = blockIdx.y*16;
  int tid = threadIdx.x;
  for (int idx = tid; idx < 2048; idx += 256) {
    int k = idx >> 8, rem = idx & 255, row = rem >> 4, r = rem & 15;
    tS[k][row][r] = t8[((u64)k*2048 + i0 + row)*16 + r];
    vS[k][row][r] = Vs[((u64)k*2048 + j0 + row)*16 + r];
  }
  __syncthreads();
  int ii = tid >> 4, jj = tid & 15;
  int i = i0 + ii, j = j0 + jj;
  float corr = 0.f;
  for (int k = 0; k < 8; ++k) {
    float m = masks[((u64)k*2048 + i)*2048 + j];
    float dv = 0.f;
    #pragma unroll
    for (int r = 0; r < 16; ++r) dv += tS[k][ii][r]*vS[k][jj][r];
    corr += alpha[k]*m*dv;
  }
  float val = adj[(u64)i*2048 + j] + corr;
  oadj[(u64)i*2048 + j] = val;
  out0[(u64)i*2048 + j] = val;
}

__global__ void kFinal(const float* __restrict__ C, float* __restrict__ out1) {
  int gid = blockIdx.x*256 + threadIdx.x;
  if (gid >= 2048*2048) return;
  int i = gid >> 11, j = gid & 2047;
  float v;
  if (i == j) v = 1.0f;
  else v = 0.5f*(C[gid] + C[(u64)j*2048 + i]);
  out1[gid] = fabsf(v);
}

// ================= host =================

extern "C" void kernel_launch(void* const* d_in, const int* in_sizes, int n_in,
                              void* d_out, int out_size, void* d_ws, size_t ws_size,
                              hipStream_t stream) {
  const float* A      = (const float*)d_in[0];
  const float* X      = (const float*)d_in[1];
  const float* W      = (const float*)d_in[2];
  const float* Us     = (const float*)d_in[3];
  const float* Vs     = (const float*)d_in[4];
  const float* alphas = (const float*)d_in[5];
  const float* masks  = (const float*)d_in[6];

  char* ws = (char*)d_ws;
  double* A64  = (double*)(ws + OFF_A64);
  float*  Vt   = (float*) (ws + OFF_VT);
  double* tau  = (double*)(ws + OFF_TAU);
  double* d64  = (double*)(ws + OFF_D64);
  double* e64  = (double*)(ws + OFF_E64);
  double* diagP = (double*)(ws + OFF_XA);
  unsigned* flags = (unsigned*)(ws + OFF_XB);
  double* y1a  = (double*)(ws + OFF_Y1A);
  double* y1b  = (double*)(ws + OFF_Y1B);
  double* y2a  = (double*)(ws + OFF_Y2A);
  double* y2b  = (double*)(ws + OFF_Y2B);
  double* SCDB = (double*)(ws + OFF_SCDB);
  int*    SCIB = (int*)   (ws + OFF_SCIB);
  int*    KNB  = (int*)   (ws + OFF_KNB);
  double* KNDB = (double*)(ws + OFF_KNDB);
  float*  ALPH = (float*) (ws + OFF_ALPHA);
  float*  Qa   = (float*) (ws + OFF_QA);
  float*  Qb   = (float*) (ws + OFF_QB);
  float*  Shat = (float*) (ws + OFF_SHAT);
  float*  Wc   = (float*) (ws + OFF_WC);
  float*  M1   = (float*) (ws + OFF_M1);
  float*  T8   = (float*) (ws + OFF_T8);
  float*  ADJ  = (float*) (ws + OFF_ADJ);
  float*  OADJ = (float*) (ws + OFF_OADJ);
  float*  CB   = (float*) (ws + OFF_CBUF);

  float* out0 = (float*)d_out;                 // reference outputs are float32
  float* out1 = out0 + (u64)2048*2048;

  // --- tridiagonalization: 1 persistent launch, flag barrier ---
  hipMemsetAsync(ws + OFF_XB, 0, 1024, stream);    // zero 256 barrier flags each run
  kCopyA<<<4096, 256, 0, stream>>>(A, A64);
  {
    void* kargs[] = { (void*)&A64, (void*)&y1a, (void*)&y1b, (void*)&y2a, (void*)&y2b,
                      (void*)&diagP, (void*)&flags,
                      (void*)&tau, (void*)&e64, (void*)&d64, (void*)&Vt };
    hipLaunchCooperativeKernel((void*)kTriDiag, dim3(TD_NBLK), dim3(256), kargs, 0, stream);
  }

  // --- D&C: leaves, batched merges (cuts folded into kTriDiag tail) ---
  hipMemsetAsync(Qa, 0, (size_t)4*MBYTE, stream);
  kLeaf<<<64, 64, 0, stream>>>(d64, e64, Qa);

  for (int lvl = 0; lvl < 6; ++lvl) {
    int bs = 16 << lvl;
    int n = 2*bs;
    int cnt = 1024/n;
    kDeflateB<<<cnt, 1024, 0, stream>>>(Qa, d64, e64, SCDB, SCIB, KNB, KNDB, bs);
    kSecularB<<<dim3((n + 3)/4, cnt), 256, 0, stream>>>(SCDB, KNB, KNDB);
    kZhatB<<<dim3((n + 63)/64, cnt), 64, 0, stream>>>(SCDB, KNB);
    kSortPermB<<<cnt, 1024, 0, stream>>>(SCDB, SCIB, KNB, d64, bs);
    kSvecNormB<<<dim3(n, cnt), 256, 0, stream>>>(Shat, SCDB, KNB, bs);
    kGatherB<<<dim3((n*n + 255)/256, cnt), 256, 0, stream>>>(Qa, Qb, SCIB, KNB, bs);
    kGemmMergeB<<<dim3(n/16, n/16, cnt), dim3(16, 16), 0, stream>>>(Qb, Shat, Qa, SCIB, KNB, bs);
    kScatterDeflB<<<dim3((n*n + 255)/256, cnt), 256, 0, stream>>>(Qb, Qa, SCIB, KNB, bs);
  }

  // --- back-transform: Qa = U (eigenvectors of A, ascending) ---
  kBackx<<<64, 256, 0, stream>>>(Qa, Vt, tau);

  // --- downstream pipeline ---
  kWc<<<8192, 256, 0, stream>>>(W, Wc);
  // M1 = U^T @ X  (1024 x 2048)
  gemm_f32<1,0><<<dim3(16, 8), 256, 0, stream>>>(Qa, X, M1, 1024, 2048, 1024, 1024, 2048, 2048);
  // f_d = Wc @ M1 (2048 x 2048) -> ADJ
  gemm_f32<0,0><<<dim3(16, 16), 256, 0, stream>>>(Wc, M1, ADJ, 2048, 2048, 1024, 1024, 2048, 2048);
  kAbsDiag<<<16384, 256, 0, stream>>>(ADJ);
  kTk<<<dim3(128, 8), 256, 0, stream>>>(ADJ, masks, Us, T8);
  kAlpha<<<1, 64, 0, stream>>>(alphas, ALPH);
  kOutAdj<<<dim3(128, 128), 256, 0, stream>>>(ADJ, masks, Vs, T8, ALPH, OADJ, out0);
  // C = out_adj @ out_adj^T
  gemm_f32<0,1><<<dim3(16, 16), 256, 0, stream>>>(OADJ, OADJ, CB, 2048, 2048, 2048, 2048, 2048, 2048);
  kFinal<<<16384, 256, 0, stream>>>(CB, out1);
}

// Round 5
// 20269.051 us; speedup vs baseline: 1.8905x; 1.8905x over previous
//
#include <hip/hip_runtime.h>
#include <hip/hip_bf16.h>

typedef unsigned long long u64;

#define MBYTE (1ull << 20)

// ---------------- workspace layout (bytes) ----------------
static const size_t OFF_A64   = 0;                    // 1024^2 f64 (8MB)
static const size_t OFF_VT    = 8*MBYTE;              // 1024^2 f32 (4MB) reflectors transposed
static const size_t OFF_TAU   = 12*MBYTE;             // 1024 f64
static const size_t OFF_D64   = 12*MBYTE +  8192;
static const size_t OFF_E64   = 12*MBYTE + 16384;
static const size_t OFF_XB    = 12*MBYTE + 24576;     // barrier flags (64 x 64B-padded u32)
static const size_t OFF_Y2B   = 12*MBYTE + 32768;     // y2 pong
static const size_t OFF_Y1B   = 12*MBYTE + 40960;     // y1 pong
static const size_t OFF_XA    = 12*MBYTE + 49152;     // diag publication (1024 f64)
static const size_t OFF_Y1A   = 12*MBYTE + 57344;     // y1 ping
static const size_t OFF_Y2A   = 12*MBYTE + 65536;     // y2 ping
static const size_t OFF_QA    = 13*MBYTE;             // 4MB f32 (D&C Q, later U)
static const size_t OFF_QB    = 17*MBYTE;             // 4MB f32
static const size_t OFF_SHAT  = 21*MBYTE;             // 4MB f32
static const size_t OFF_WC    = 25*MBYTE;             // 8MB f32; during D&C holds batched merge scratch
static const size_t OFF_M1    = 33*MBYTE;             // 8MB f32
static const size_t OFF_T8    = 33*MBYTE;             // 2MB f32 (reuses M1, dead by then)
static const size_t OFF_ALPHA = 35*MBYTE + 512*1024;  // float[8] (dead region)
static const size_t OFF_ADJ   = 41*MBYTE;             // 16MB f32
static const size_t OFF_OADJ  = 17*MBYTE;             // 16MB f32 (reuses QB/SHAT/WC, dead)
static const size_t OFF_CBUF  = 0;                    // 16MB f32 (reuses A64/VT/QA, dead)

// batched D&C scratch inside the (dead-during-D&C) WC region
static const size_t SCD_STRIDE = 9216;   // doubles per merge
static const size_t SCI_STRIDE = 6144;   // ints per merge
static const size_t OFF_SCDB  = OFF_WC;                       // 32*9216*8 = 2359296
static const size_t OFF_SCIB  = OFF_WC + 2359296;             // 32*6144*4 = 786432
static const size_t OFF_KNB   = OFF_WC + 2359296 + 786432;    // 32*8 ints
static const size_t OFF_KNDB  = OFF_WC + 2359296 + 786432 + 2048; // 32*4 dbl

// ================= tridiagonalization (ssytd2-faithful, lower, f64) =================
// PERSISTENT kernel, 64 blocks x 1024 threads (round-3 geometry: the measured
// sweet spot -- round 4 showed barrier/staging contention scales with blocks).
//   wave g (= wave*64 + bid) owns row g of A64 -> rows block-private, L2-resident,
//   no flush in the loop. Cross-block data (y1/y2/diag ~24KB/step) via relaxed
//   agent-scope atomics. Changes vs round 3 (scheduling only, numerics identical):
//   - y1/y2 staged to LDS with ONE parallel load per thread (1024 threads),
//     overlapped with the norm pass, replacing 4-deep serialized atomic loads.
//   - Phase A passes fused: 5 intra-step syncs instead of 8.
//   - Flag barrier (64B-padded flags, parallel arrivals) replaces the serialized
//     single-counter fetch_add chain.

__global__ void kCopyA(const float* __restrict__ A, double* __restrict__ A64) {
  int gid = blockIdx.x*256 + threadIdx.x;
  if (gid < 1024*1024) A64[gid] = (double)A[gid];
}

__device__ __forceinline__ double agLoadD(const double* p) {
  return __hip_atomic_load(p, __ATOMIC_RELAXED, __HIP_MEMORY_SCOPE_AGENT);
}
__device__ __forceinline__ void agStoreD(double* p, double v) {
  __hip_atomic_store(p, v, __ATOMIC_RELAXED, __HIP_MEMORY_SCOPE_AGENT);
}

#define TD_NBLK 64

__global__ __launch_bounds__(1024) void kTriDiag(
    double* __restrict__ A64,
    double* __restrict__ y1A, double* __restrict__ y1B,
    double* __restrict__ y2A, double* __restrict__ y2B,
    double* __restrict__ diagP, unsigned* __restrict__ flags,
    double* __restrict__ tauv, double* __restrict__ e64, double* __restrict__ d64,
    float* __restrict__ Vt) {
  __shared__ double xL[1024], vL[1024], wL[1024], y1L[1024], y2L[1024];
  __shared__ double red[4];
  __shared__ double sS[4];
  int tid = threadIdx.x;
  int bid = blockIdx.x;
  bool w0 = (bid == 0);
  int lane = tid & 63, wave = tid >> 6;   // 16 waves
  int myRow = wave*TD_NBLK + bid;         // bijective 0..1023

  double dg = 0.0;                        // diag prefetch register (thread 0 of block 0)

  for (int i = 0; i <= 1023; ++i) {
    const double* y1in = (((i-1)&1) != 0) ? y1B : y1A;   // only used for i>=1
    const double* y2in = (((i-1)&1) != 0) ? y2B : y2A;
    double* y1out = ((i&1) != 0) ? y1B : y1A;
    double* y2out = ((i&1) != 0) ? y2B : y2A;

    if (i == 0) {
      if (tid < 256) {
        for (int c = tid; c < 1024; c += 256) { vL[c] = 0.0; wL[c] = 0.0; }
        for (int c = 1 + tid; c < 1024; c += 256) xL[c] = A64[(u64)c*1024];
        if (w0 && tid == 0) d64[0] = A64[0];
      }
      __syncthreads();
    } else {
      int j = i - 1;                       // reflector being finalized
      // ---- stage y into LDS: one parallel agent load per thread (1024 threads),
      //      overlapped with the norm pass (waves 0-3, LDS-only, no dependency) ----
      double sy1 = agLoadD(&y1in[tid]);
      double sy2 = agLoadD(&y2in[tid]);
      if (w0 && tid == 0) dg = agLoadD(&diagP[i]);
      double acc = 0.0;
      if (tid < 256) {
        for (int c = i + 1 + tid; c < 1024; c += 256) { double v = xL[c]; acc += v*v; }
        for (int off = 32; off > 0; off >>= 1) acc += __shfl_xor(acc, off, 64);
      }
      y1L[tid] = sy1; y2L[tid] = sy2;      // waitcnt lands here, after the norm pass
      if (tid < 256 && lane == 0) red[wave] = acc;
      __syncthreads();                                   // S1
      if (tid == 0) {
        double xn2 = red[0] + red[1] + red[2] + red[3];
        double alpha = xL[i];
        double tv, sc;
        if (xn2 == 0.0) { tv = 0.0; if (w0) e64[j] = alpha; sc = 0.0; }
        else {
          double beta = (alpha >= 0.0) ? -sqrt(alpha*alpha + xn2) : sqrt(alpha*alpha + xn2);
          tv = (beta - alpha)/beta;
          if (w0) e64[j] = beta;
          sc = 1.0/(alpha - beta);
        }
        if (w0) tauv[j] = tv;
        sS[0] = sc; sS[1] = tv;
        vL[i] = 1.0;
        if (w0) Vt[(u64)j*1024 + i] = 1.0f;
      }
      __syncthreads();                                   // S2
      if (tid < 256) {
        // fused v-scale + P pass (same per-element values/order as separate passes)
        double sc = sS[0], tv = sS[1];
        double acc2 = 0.0;
        for (int r = i + tid; r < 1024; r += 256) {
          double v;
          if (r == i) v = 1.0;
          else {
            v = xL[r]*sc;
            vL[r] = v;
            if (w0) Vt[(u64)j*1024 + r] = (float)v;
          }
          double P = tv*(y1L[r] + sc*y2L[r]);
          wL[r] = P;
          acc2 += P*v;
        }
        for (int off = 32; off > 0; off >>= 1) acc2 += __shfl_xor(acc2, off, 64);
        if (lane == 0) red[wave] = acc2;
      }
      __syncthreads();                                   // S3
      if (tid == 0) {
        double coef = 0.5*sS[1]*(red[0] + red[1] + red[2] + red[3]);
        double wi = wL[i] - coef;    // == corrected wL[i] (vL[i]=1)
        sS[2] = coef; sS[3] = wi;
        if (w0) d64[i] = dg - 2.0*wi;
      }
      __syncthreads();                                   // S4
      if (tid < 256) {
        // fused w-correction + x-update
        double coef = sS[2], wi = sS[3];
        for (int r = i + tid; r < 1024; r += 256) {
          double wcr = wL[r] - coef*vL[r];
          wL[r] = wcr;
          if (r > i) xL[r] = y1L[r] - vL[r]*wi - wcr;
        }
      }
      __syncthreads();                                   // S5
    }
    // ---- Phase B: rank-2 apply to OWN row fused with y1/y2 = A'*x ----
    if (i <= 1022) {
      int r = myRow;
      if (r >= i + 1) {
        double vr = vL[r], wr = wL[r];
        double* Arow = A64 + (u64)r*1024;
        double acc = 0.0, y1v = 0.0;
        for (int c = i + 1 + lane; c < 1024; c += 64) {
          double a = Arow[c] - vr*wL[c] - wr*vL[c];
          Arow[c] = a;
          if (c == r) agStoreD(&diagP[r], a);      // publish diagonal
          if (c == i + 1) y1v = a; else acc += a*xL[c];
        }
        for (int off = 32; off > 0; off >>= 1) acc += __shfl_down(acc, off, 64);
        if (lane == 0) { agStoreD(&y1out[r], y1v); agStoreD(&y2out[r], acc); }
      }
      // all waves' Phase B stores drained before arrival (waitcnt at the barrier)
      __syncthreads();                                   // S6
      // ---- flag barrier: parallel release stores + wave-0 parallel acquire spin ----
      unsigned tgt = (unsigned)(i + 1);
      if (tid == 0)
        __hip_atomic_store(&flags[bid*16], tgt, __ATOMIC_RELEASE, __HIP_MEMORY_SCOPE_AGENT);
      if (tid < TD_NBLK) {
        for (;;) {
          unsigned v = __hip_atomic_load(&flags[tid*16], __ATOMIC_ACQUIRE, __HIP_MEMORY_SCOPE_AGENT);
          if (__all(v >= tgt)) break;
          __builtin_amdgcn_s_sleep(2);
        }
      }
      __syncthreads();                                   // S7
    }
  }
  // folded kCuts (block-0 thread-0 local data only)
  if (w0 && tid == 0) {
    for (int c = 16; c < 1024; c += 16) {
      double ae = fabs(e64[c-1]);
      d64[c-1] -= ae;
      d64[c]   -= ae;
    }
  }
}

// ================= ssteqr (leaves, n=16, COMPZ='I') =================

__device__ void slartg_(double f, double g, double* cs, double* sn, double* r) {
  if (g == 0.0) { *cs = 1.0; *sn = 0.0; *r = f; }
  else if (f == 0.0) { *cs = 0.0; *sn = (g >= 0.0) ? 1.0 : -1.0; *r = fabs(g); }
  else {
    double d = sqrt(f*f + g*g);
    *cs = fabs(f)/d;
    *r = (f >= 0.0) ? d : -d;
    *sn = g / (*r);
  }
}

__device__ void slaev2_(double a, double b, double c, double* rt1, double* rt2,
                        double* cs1, double* sn1) {
  double sm = a + c, df = a - c, adf = fabs(df), tb = b + b, ab = fabs(tb);
  double acmx, acmn;
  if (fabs(a) > fabs(c)) { acmx = a; acmn = c; } else { acmx = c; acmn = a; }
  double rt;
  if (adf > ab) rt = adf*sqrt(1.0 + (ab/adf)*(ab/adf));
  else if (adf < ab) rt = ab*sqrt(1.0 + (adf/ab)*(adf/ab));
  else rt = ab*sqrt(2.0);
  int sgn1;
  if (sm < 0.0) { *rt1 = 0.5*(sm - rt); sgn1 = -1; *rt2 = (acmx / *rt1)*acmn - (b / *rt1)*b; }
  else if (sm > 0.0) { *rt1 = 0.5*(sm + rt); sgn1 = 1; *rt2 = (acmx / *rt1)*acmn - (b / *rt1)*b; }
  else { *rt1 = 0.5*rt; *rt2 = -0.5*rt; sgn1 = 1; }
  int sgn2; double cs;
  if (df >= 0.0) { cs = df + rt; sgn2 = 1; } else { cs = df - rt; sgn2 = -1; }
  double acs = fabs(cs);
  if (acs > ab) { double ct = -tb/cs; *sn1 = 1.0/sqrt(1.0 + ct*ct); *cs1 = ct*(*sn1); }
  else {
    if (ab == 0.0) { *cs1 = 1.0; *sn1 = 0.0; }
    else { double tn = -cs/tb; *cs1 = 1.0/sqrt(1.0 + tn*tn); *sn1 = tn*(*cs1); }
  }
  if (sgn1 == sgn2) { double tn = *cs1; *cs1 = -(*sn1); *sn1 = tn; }
}

__device__ void steqr16_(double* d, double* e, double* z, double* wc, double* ws_) {
  const int n = 16;
  const double eps = 5.9604644775390625e-08;
  const double eps2 = eps*eps;
  const double safmin = 1.1754943508222875e-38;
  int jtot = 0; const int nmaxit = n*30;
  int l1 = 0;
  for (int outer = 0; outer < 200; ++outer) {
    if (l1 > n-1) break;
    if (l1 > 0) e[l1-1] = 0.0;
    int m = l1;
    for (; m <= n-2; ++m) {
      double tst = fabs(e[m]);
      if (tst == 0.0) break;
      if (tst <= (sqrt(fabs(d[m]))*sqrt(fabs(d[m+1])))*eps) { e[m] = 0.0; break; }
    }
    int l = l1, lend = m;
    l1 = m + 1;
    if (lend == l) continue;
    if (fabs(d[lend]) < fabs(d[l])) { int t = l; l = lend; lend = t; }
    if (lend > l) {
      for (int it = 0; it < 800; ++it) {
        int mm = lend;
        if (l != lend) {
          for (mm = l; mm <= lend-1; ++mm) {
            double tst = e[mm]*e[mm];
            if (tst <= eps2*fabs(d[mm])*fabs(d[mm+1]) + safmin) break;
          }
        }
        if (mm < lend) e[mm] = 0.0;
        double p = d[l];
        if (mm == l) { d[l] = p; ++l; if (l <= lend) continue; break; }
        if (mm == l+1) {
          double rt1, rt2, c2, s2;
          slaev2_(d[l], e[l], d[l+1], &rt1, &rt2, &c2, &s2);
          for (int r = 0; r < n; ++r) {
            double t = z[r*16 + l + 1];
            z[r*16 + l + 1] = c2*t - s2*z[r*16 + l];
            z[r*16 + l]     = s2*t + c2*z[r*16 + l];
          }
          d[l] = rt1; d[l+1] = rt2; e[l] = 0.0;
          l += 2; if (l <= lend) continue; break;
        }
        if (jtot == nmaxit) break;
        ++jtot;
        double g = (d[l+1] - p)/(2.0*e[l]);
        double r_ = sqrt(g*g + 1.0);
        g = d[mm] - p + e[l]/(g + ((g >= 0.0) ? r_ : -r_));
        double s = 1.0, c = 1.0;
        p = 0.0;
        for (int i = mm-1; i >= l; --i) {
          double f = s*e[i], b = c*e[i];
          double cs, sn, rr;
          slartg_(g, f, &cs, &sn, &rr);
          c = cs; s = sn;
          if (i != mm-1) e[i+1] = rr;
          g = d[i+1] - p;
          rr = (d[i] - g)*s + 2.0*c*b;
          p = s*rr;
          d[i+1] = g + p;
          g = c*rr - b;
          wc[i] = c; ws_[i] = -s;
        }
        for (int jj = mm-1; jj >= l; --jj) {
          double cs = wc[jj], sn = ws_[jj];
          for (int r = 0; r < n; ++r) {
            double t = z[r*16 + jj + 1];
            z[r*16 + jj + 1] = cs*t - sn*z[r*16 + jj];
            z[r*16 + jj]     = sn*t + cs*z[r*16 + jj];
          }
        }
        d[l] -= p;
        e[l] = g;
      }
    } else {
      for (int it = 0; it < 800; ++it) {
        int mm = lend;
        if (l != lend) {
          for (mm = l; mm >= lend+1; --mm) {
            double tst = e[mm-1]*e[mm-1];
            if (tst <= eps2*fabs(d[mm])*fabs(d[mm-1]) + safmin) break;
          }
        }
        if (mm > lend) e[mm-1] = 0.0;
        double p = d[l];
        if (mm == l) { d[l] = p; --l; if (l >= lend) continue; break; }
        if (mm == l-1) {
          double rt1, rt2, c2, s2;
          slaev2_(d[l-1], e[l-1], d[l], &rt1, &rt2, &c2, &s2);
          for (int r = 0; r < n; ++r) {
            double t = z[r*16 + l];
            z[r*16 + l]     = c2*t - s2*z[r*16 + l - 1];
            z[r*16 + l - 1] = s2*t + c2*z[r*16 + l - 1];
          }
          d[l-1] = rt1; d[l] = rt2; e[l-1] = 0.0;
          l -= 2; if (l >= lend) continue; break;
        }
        if (jtot == nmaxit) break;
        ++jtot;
        double g = (d[l-1] - p)/(2.0*e[l-1]);
        double r_ = sqrt(g*g + 1.0);
        g = d[mm] - p + e[l-1]/(g + ((g >= 0.0) ? r_ : -r_));
        double s = 1.0, c = 1.0;
        p = 0.0;
        for (int i = mm; i <= l-1; ++i) {
          double f = s*e[i], b = c*e[i];
          double cs, sn, rr;
          slartg_(g, f, &cs, &sn, &rr);
          c = cs; s = sn;
          if (i != mm) e[i-1] = rr;
          g = d[i] - p;
          rr = (d[i+1] - g)*s + 2.0*c*b;
          p = s*rr;
          d[i] = g + p;
          g = c*rr - b;
          wc[i] = c; ws_[i] = s;
        }
        for (int jj = mm; jj <= l-1; ++jj) {
          double cs = wc[jj], sn = ws_[jj];
          for (int r = 0; r < n; ++r) {
            double t = z[r*16 + jj + 1];
            z[r*16 + jj + 1] = cs*t - sn*z[r*16 + jj];
            z[r*16 + jj]     = sn*t + cs*z[r*16 + jj];
          }
        }
        d[l] -= p;
        e[l-1] = g;
      }
    }
  }
  for (int ii = 1; ii <= n-1; ++ii) {
    int i = ii - 1, k = i;
    double p = d[i];
    for (int j = ii; j <= n-1; ++j) if (d[j] < p) { k = j; p = d[j]; }
    if (k != i) {
      d[k] = d[i]; d[i] = p;
      for (int r = 0; r < n; ++r) { double t = z[r*16 + i]; z[r*16 + i] = z[r*16 + k]; z[r*16 + k] = t; }
    }
  }
}

__global__ void kLeaf(double* d64, const double* e64, float* Qa) {
  __shared__ double dd[16], ed[16], zd[256], wk1[16], wk2[16];
  int leaf = blockIdx.x, lo = leaf*16, tid = threadIdx.x;
  for (int idx = tid; idx < 256; idx += 64) zd[idx] = ((idx/16) == (idx%16)) ? 1.0 : 0.0;
  if (tid < 16) { dd[tid] = d64[lo + tid]; ed[tid] = (tid < 15) ? e64[lo + tid] : 0.0; }
  __syncthreads();
  if (tid == 0) steqr16_(dd, ed, zd, wk1, wk2);
  __syncthreads();
  for (int idx = tid; idx < 256; idx += 64) {
    int r = idx/16, c = idx%16;
    Qa[(u64)(lo + r)*1024 + lo + c] = (float)zd[idx];
  }
  if (tid < 16) d64[lo + tid] = dd[tid];
}

// ================= batched D&C merge =================
// scd per-merge (doubles): 1024 dl | 2048 wm | 3072 mu | 4096 zh | 7168 dval
// sci per-merge (ints):    0 permsec | 1024 deflc | 4096 rootpos | 5120 dpos

__global__ __launch_bounds__(1024) void kDeflateB(float* __restrict__ Qa,
      const double* __restrict__ d64, const double* __restrict__ e64,
      double* scdB, int* sciB, int* knB, double* kndB, int bs) {
  __shared__ double zL[1024], dlocL[1024], redD[1024];
  __shared__ double rcL[1024], rsL[1024];
  __shared__ int sIdxL[1024], rpqL[1024];
  __shared__ double sSc[4];
  __shared__ int sKn[4];
  int mg = blockIdx.x;
  int n1 = bs, n = 2*bs, lo = mg*n;
  double* scd = scdB + (u64)mg*SCD_STRIDE;
  int*    sci = sciB + (u64)mg*SCI_STRIDE;
  int* kn = knB + mg*8;
  double* knd = kndB + mg*4;
  int tid = threadIdx.x;
  if (tid == 0) sSc[0] = e64[lo + n1 - 1];
  __syncthreads();
  double rho_in = sSc[0];
  const double invs2 = 0.70710678118654752440;
  if (tid < n) {
    int row = (tid < n1) ? (lo + n1 - 1) : (lo + n1);
    double s = (rho_in < 0.0 && tid >= n1) ? -invs2 : invs2;
    zL[tid] = (double)Qa[(u64)row*1024 + lo + tid] * s;
    dlocL[tid] = d64[lo + tid];
  }
  __syncthreads();
  if (tid < n) {
    int pos; double key = dlocL[tid];
    if (tid < n1) {
      int loB = 0, hiB = n - n1;
      while (loB < hiB) { int mid = (loB+hiB)>>1; if (dlocL[n1+mid] < key) loB = mid+1; else hiB = mid; }
      pos = tid + loB;
    } else {
      int loA = 0, hiA = n1;
      while (loA < hiA) { int mid = (loA+hiA)>>1; if (dlocL[mid] <= key) loA = mid+1; else hiA = mid; }
      pos = (tid - n1) + loA;
    }
    sIdxL[pos] = tid;
  }
  redD[tid] = (tid < n) ? fabs(zL[tid]) : 0.0;
  __syncthreads();
  for (int s = 512; s > 0; s >>= 1) { if (tid < s) redD[tid] = fmax(redD[tid], redD[tid+s]); __syncthreads(); }
  if (tid == 0) sSc[1] = redD[0];
  __syncthreads();
  redD[tid] = (tid < n) ? fabs(dlocL[tid]) : 0.0;
  __syncthreads();
  for (int s = 512; s > 0; s >>= 1) { if (tid < s) redD[tid] = fmax(redD[tid], redD[tid+s]); __syncthreads(); }
  if (tid == 0) {
    double zmax = sSc[1], dmax = redD[0];
    double rho = fabs(2.0*rho_in);
    double tol = 8.0*5.9604644775390625e-8*fmax(dmax, zmax);
    double* dlG = scd + 1024;
    double* wmG = scd + 2048;
    double* dvalG = scd + 7168;
    int* permG = sci;
    int* deflG = sci + 1024;
    int K = 0, nrot = 0, nd = 0; double sw2 = 0.0;
    if (rho*zmax <= tol) {
      for (int pos = 0; pos < n; ++pos) { int c = sIdxL[pos]; deflG[nd] = c; dvalG[nd] = dlocL[c]; nd++; }
    } else {
      int pj = -1, jpos = 0;
      for (; jpos < n; ++jpos) {
        int nj = sIdxL[jpos];
        if (rho*fabs(zL[nj]) <= tol) { deflG[nd] = nj; dvalG[nd] = dlocL[nj]; nd++; }
        else { pj = nj; break; }
      }
      for (++jpos; jpos < n; ++jpos) {
        int nj = sIdxL[jpos];
        if (rho*fabs(zL[nj]) <= tol) { deflG[nd] = nj; dvalG[nd] = dlocL[nj]; nd++; continue; }
        double s_ = zL[pj], c_ = zL[nj];
        double tu = sqrt(c_*c_ + s_*s_);
        double tdif = dlocL[nj] - dlocL[pj];
        c_ /= tu; s_ = -s_/tu;
        if (fabs(tdif*c_*s_) <= tol) {
          zL[nj] = tu; zL[pj] = 0.0;
          rpqL[nrot] = (pj << 16) | nj; rcL[nrot] = c_; rsL[nrot] = s_; nrot++;
          double t1 = dlocL[pj]*c_*c_ + dlocL[nj]*s_*s_;
          dlocL[nj] = dlocL[pj]*s_*s_ + dlocL[nj]*c_*c_;
          dlocL[pj] = t1;
          deflG[nd] = pj; dvalG[nd] = t1; nd++;
          pj = nj;
        } else {
          permG[K] = pj; dlG[K] = dlocL[pj]; wmG[K] = zL[pj]; sw2 += zL[pj]*zL[pj]; K++;
          pj = nj;
        }
      }
      permG[K] = pj; dlG[K] = dlocL[pj]; wmG[K] = zL[pj]; sw2 += zL[pj]*zL[pj]; K++;
    }
    sKn[1] = nrot;
    kn[0] = K; kn[1] = nrot; kn[2] = nd;
    knd[0] = rho; knd[1] = sw2;
  }
  __syncthreads();
  int nrot = sKn[1];
  if (tid < n && nrot > 0) {
    u64 row = (u64)(lo + tid)*1024;
    for (int t = 0; t < nrot; ++t) {
      int pq = rpqL[t];
      int p = lo + (pq >> 16), q = lo + (pq & 0xffff);
      double c = rcL[t], s = rsL[t];
      double x = (double)Qa[row + p], y = (double)Qa[row + q];
      Qa[row + p] = (float)(c*x + s*y);
      Qa[row + q] = (float)(c*y - s*x);
    }
  }
}

__global__ __launch_bounds__(256) void kSecularB(double* scdB, const int* knB, const double* kndB) {
  __shared__ double dlS[1024], wmS[1024];
  int mg = blockIdx.y;
  double* scd = scdB + (u64)mg*SCD_STRIDE;
  const int* kn = knB + mg*8;
  const double* knd = kndB + mg*4;
  int K = kn[0];
  int tid = threadIdx.x;
  for (int j = tid; j < K; j += 256) { dlS[j] = scd[1024 + j]; wmS[j] = scd[2048 + j]; }
  __syncthreads();
  int wave = tid >> 6, lane = tid & 63;
  int i = blockIdx.x*4 + wave;
  if (i >= K) return;
  double rho = knd[0], sw2 = knd[1];
  double di = dlS[i];
  double hi = (i < K-1) ? (dlS[i+1] - di) : (rho*sw2*(1.0 + 1e-12) + 1e-300);
  double lo_ = 0.0;
  for (int it = 0; it < 100; ++it) {
    double mid = 0.5*(lo_ + hi);
    double g = 0.0;
    for (int j = lane; j < K; j += 64) { double w = wmS[j]; g += w*w/((dlS[j] - di) - mid); }
    for (int off = 32; off > 0; off >>= 1) g += __shfl_xor(g, off);
    g = 1.0 + rho*g;
    if (g < 0.0) lo_ = mid; else hi = mid;
  }
  scd[3072 + i] = 0.5*(lo_ + hi);
}

__global__ void kZhatB(double* scdB, const int* knB) {
  int mg = blockIdx.y;
  double* scd = scdB + (u64)mg*SCD_STRIDE;
  int K = (knB + mg*8)[0];
  int j = blockIdx.x*64 + threadIdx.x;
  if (j >= K) return;
  const double* dl = scd + 1024;
  const double* wm = scd + 2048;
  const double* mu = scd + 3072;
  double dj = dl[j];
  double prod = mu[j];
  for (int i2 = 0; i2 < K; ++i2) {
    if (i2 == j) continue;
    double dd = dl[i2] - dj;
    prod *= (dd + mu[i2]) / dd;
  }
  prod = fabs(prod);
  scd[4096 + j] = (wm[j] >= 0.0) ? sqrt(prod) : -sqrt(prod);
}

__global__ __launch_bounds__(1024) void kSortPermB(double* scdB, int* sciB, const int* knB,
                                                   double* d64, int bs) {
  __shared__ double sv[1024];
  __shared__ int si[1024];
  int mg = blockIdx.x;
  int n = 2*bs, lo = mg*n;
  double* scd = scdB + (u64)mg*SCD_STRIDE;
  int* sci = sciB + (u64)mg*SCI_STRIDE;
  int K = (knB + mg*8)[0];
  int tid = threadIdx.x;
  const double* dl = scd + 1024;
  const double* mu = scd + 3072;
  const double* dval = scd + 7168;
  double v;
  if (tid < K) v = dl[tid] + mu[tid];
  else if (tid < n) v = dval[tid - K];
  else v = 1e300;
  sv[tid] = v; si[tid] = tid;
  __syncthreads();
  for (int k = 2; k <= 1024; k <<= 1) {
    for (int j = k >> 1; j > 0; j >>= 1) {
      int ixj = tid ^ j;
      if (ixj > tid) {
        bool up = ((tid & k) == 0);
        double a = sv[tid], b = sv[ixj];
        int ia = si[tid], ib = si[ixj];
        bool agtb = (a > b) || (a == b && ia > ib);
        if (up ? agtb : !agtb) { sv[tid] = b; sv[ixj] = a; si[tid] = ib; si[ixj] = ia; }
      }
      __syncthreads();
    }
  }
  if (tid < n) {
    int s = si[tid];
    if (s < K) sci[4096 + s] = tid; else sci[5120 + s - K] = tid;
    d64[lo + tid] = sv[tid];
  }
}

__global__ void kSvecNormB(float* __restrict__ Shat, const double* scdB, const int* knB, int bs) {
  int mg = blockIdx.y;
  int n = 2*bs, lo = mg*n;
  const double* scd = scdB + (u64)mg*SCD_STRIDE;
  int K = (knB + mg*8)[0];
  int i = blockIdx.x;
  if (i >= K) return;
  const double* dl = scd + 1024;
  const double* mu = scd + 3072;
  const double* zh = scd + 4096;
  __shared__ double red[256];
  int tid = threadIdx.x;
  double di = dl[i], m = mu[i];
  double acc = 0.0;
  for (int j = tid; j < K; j += 256) {
    double v = zh[j]/((dl[j] - di) - m);
    acc += v*v;
  }
  red[tid] = acc; __syncthreads();
  for (int s = 128; s > 0; s >>= 1) { if (tid < s) red[tid] += red[tid+s]; __syncthreads(); }
  double inv = 1.0/sqrt(red[0]);
  for (int j = tid; j < K; j += 256) {
    double v = zh[j]/((dl[j] - di) - m);
    Shat[(u64)j*1024 + lo + i] = (float)(v*inv);
  }
}

__global__ void kGatherB(const float* Qa, float* Qb, const int* sciB, const int* knB, int bs) {
  int mg = blockIdx.y;
  int n = 2*bs, lo = mg*n;
  const int* sci = sciB + (u64)mg*SCI_STRIDE;
  int K = (knB + mg*8)[0];
  int gid = blockIdx.x*256 + threadIdx.x;
  if (gid >= n*n) return;
  int p = gid % n, r = gid / n;
  int src = (p < K) ? sci[p] : sci[1024 + p - K];
  Qb[(u64)(lo + r)*1024 + p] = Qa[(u64)(lo + r)*1024 + lo + src];
}

__global__ void kGemmMergeB(const float* __restrict__ Qb, const float* __restrict__ Shat,
                            float* __restrict__ Qa, const int* sciB, const int* knB, int bs) {
  __shared__ float As[16][17], Bs[16][17];
  int mg = blockIdx.z;
  int n = 2*bs, lo = mg*n;
  const int* sci = sciB + (u64)mg*SCI_STRIDE;
  int K = (knB + mg*8)[0];
  int tx = threadIdx.x, ty = threadIdx.y;
  int r0 = blockIdx.y*16, c0 = blockIdx.x*16;
  const int* rootpos = sci + 4096;
  float acc = 0.f;
  for (int k0 = 0; k0 < K; k0 += 16) {
    As[ty][tx] = (k0 + tx < K) ? Qb[(u64)(lo + r0 + ty)*1024 + k0 + tx] : 0.f;
    Bs[ty][tx] = (k0 + ty < K && c0 + tx < K) ? Shat[(u64)(k0 + ty)*1024 + lo + c0 + tx] : 0.f;
    __syncthreads();
    #pragma unroll
    for (int kk = 0; kk < 16; ++kk) acc += As[ty][kk]*Bs[kk][tx];
    __syncthreads();
  }
  int i = c0 + tx;
  if (i < K) Qa[(u64)(lo + r0 + ty)*1024 + lo + rootpos[i]] = acc;
}

__global__ void kScatterDeflB(const float* Qb, float* Qa, const int* sciB, const int* knB, int bs) {
  int mg = blockIdx.y;
  int n = 2*bs, lo = mg*n;
  const int* sci = sciB + (u64)mg*SCI_STRIDE;
  const int* kn = knB + mg*8;
  int gid = blockIdx.x*256 + threadIdx.x;
  if (gid >= n*n) return;
  int p = gid % n, r = gid / n;
  int K = kn[0], nd = kn[2];
  if (p < K || p - K >= nd) return;
  Qa[(u64)(lo + r)*1024 + lo + sci[5120 + p - K]] = Qb[(u64)(lo + r)*1024 + p];
}

// ================= back-transform =================
// PAIRED reflectors: Z <- H_b H_a Z per iteration using
//   Z' = Z - ta*va*da - tb*vb*(db - ta*s*da),  s = vb^T va
// halves the serial chain (511 pairs + 1) and the Z traffic.
__global__ void kBackx(float* __restrict__ Qa, const float* __restrict__ Vt,
                       const double* __restrict__ tau) {
  __shared__ double redA[256], redB[256], redS[16];
  __shared__ double fA[16], fB[16];
  int tid = threadIdx.x;
  int cix = tid & 15, strip = tid >> 4;
  int col = blockIdx.x*16 + cix;
  for (int a = 1022; a >= 2; a -= 2) {
    int b = a - 1;
    double ta = tau[a], tb = tau[b];
    const float* va_row = Vt + (u64)a*1024;
    const float* vb_row = Vt + (u64)b*1024;
    double pda = 0.0, pdb = 0.0, ps = 0.0;
    for (int r = a + strip; r < 1024; r += 16) {
      double zb = (double)Qa[(u64)r*1024 + col];
      double va = (r > a) ? (double)va_row[r] : 0.0;   // Vt[a][a] is unwritten
      double vb = (double)vb_row[r];                   // Vt[b][a] == 1
      pda += va*zb; pdb += vb*zb;
      if (cix == 0) ps += va*vb;
    }
    redA[tid] = pda; redB[tid] = pdb;
    if (cix == 0) redS[strip] = ps;
    __syncthreads();
    if (tid < 16) {
      double da = 0.0, db = 0.0, s = 0.0;
      for (int u = 0; u < 16; ++u) {
        da += redA[u*16 + tid];
        db += redB[u*16 + tid];
        s  += redS[u];
      }
      fA[tid] = ta*da;
      fB[tid] = tb*(db - ta*s*da);
    }
    __syncthreads();
    double fa = fA[cix], fb = fB[cix];
    for (int r = a + strip; r < 1024; r += 16) {
      double va = (r > a) ? (double)va_row[r] : 0.0;
      double vb = (double)vb_row[r];
      Qa[(u64)r*1024 + col] -= (float)(fa*va + fb*vb);
    }
    __syncthreads();
  }
  // leftover reflector 0
  {
    double t0 = tau[0];
    const float* v_row = Vt;
    double pd = 0.0;
    for (int r = 1 + strip; r < 1024; r += 16)
      pd += (double)v_row[r] * (double)Qa[(u64)r*1024 + col];
    redA[tid] = pd;
    __syncthreads();
    if (tid < 16) {
      double d = 0.0;
      for (int u = 0; u < 16; ++u) d += redA[u*16 + tid];
      fA[tid] = t0*d;
    }
    __syncthreads();
    double f = fA[cix];
    for (int r = 1 + strip; r < 1024; r += 16)
      Qa[(u64)r*1024 + col] -= (float)(f * (double)v_row[r]);
  }
}

// ================= downstream math =================

// 128x128 tile, 8x8 micro-tile, BK=8, float4 everywhere
template<int TA, int TB>
__global__ __launch_bounds__(256) void gemm_f32(const float* __restrict__ A,
    const float* __restrict__ B, float* __restrict__ C,
    int M, int N, int Kd, int lda, int ldb, int ldc) {
  __shared__ float As[8][132];
  __shared__ float Bs[8][132];
  int tid = threadIdx.x;
  int bi = blockIdx.y*128, bj = blockIdx.x*128;
  int tx = tid & 15, ty = tid >> 4;
  float acc[8][8];
  #pragma unroll
  for (int x = 0; x < 8; ++x)
    #pragma unroll
    for (int y = 0; y < 8; ++y) acc[x][y] = 0.f;
  for (int k0 = 0; k0 < Kd; k0 += 8) {
    if (TA == 0) {
      int row = tid >> 1, kc = (tid & 1)*4;
      float4 v = *(const float4*)&A[(u64)(bi + row)*lda + k0 + kc];
      As[kc+0][row] = v.x; As[kc+1][row] = v.y; As[kc+2][row] = v.z; As[kc+3][row] = v.w;
    } else {
      int kk = tid >> 5, col = (tid & 31)*4;
      float4 v = *(const float4*)&A[(u64)(k0 + kk)*lda + bi + col];
      *(float4*)&As[kk][col] = v;
    }
    if (TB == 0) {
      int kk = tid >> 5, col = (tid & 31)*4;
      float4 v = *(const float4*)&B[(u64)(k0 + kk)*ldb + bj + col];
      *(float4*)&Bs[kk][col] = v;
    } else {
      int row = tid >> 1, kc = (tid & 1)*4;
      float4 v = *(const float4*)&B[(u64)(bj + row)*ldb + k0 + kc];
      Bs[kc+0][row] = v.x; Bs[kc+1][row] = v.y; Bs[kc+2][row] = v.z; Bs[kc+3][row] = v.w;
    }
    __syncthreads();
    #pragma unroll
    for (int kk = 0; kk < 8; ++kk) {
      float a[8], b[8];
      *(float4*)&a[0] = *(float4*)&As[kk][ty*8];
      *(float4*)&a[4] = *(float4*)&As[kk][ty*8 + 4];
      *(float4*)&b[0] = *(float4*)&Bs[kk][tx*8];
      *(float4*)&b[4] = *(float4*)&Bs[kk][tx*8 + 4];
      #pragma unroll
      for (int x = 0; x < 8; ++x)
        #pragma unroll
        for (int y = 0; y < 8; ++y) acc[x][y] += a[x]*b[y];
    }
    __syncthreads();
  }
  #pragma unroll
  for (int x = 0; x < 8; ++x) {
    float* Crow = &C[(u64)(bi + ty*8 + x)*ldc + bj + tx*8];
    *(float4*)&Crow[0] = make_float4(acc[x][0], acc[x][1], acc[x][2], acc[x][3]);
    *(float4*)&Crow[4] = make_float4(acc[x][4], acc[x][5], acc[x][6], acc[x][7]);
  }
}

__global__ void kWc(const float* W, float* Wc) {
  int gid = blockIdx.x*256 + threadIdx.x;
  if (gid >= 2048*1024) return;
  int i = gid >> 10, k = gid & 1023;
  Wc[gid] = W[(u64)i*2048 + k] + W[(u64)i*2048 + 1024 + k];
}

__global__ void kAbsDiag(float* adj) {
  int gid = blockIdx.x*256 + threadIdx.x;
  if (gid >= 2048*2048) return;
  int i = gid >> 11, j = gid & 2047;
  float v = fabsf(adj[gid]);
  adj[gid] = (i == j) ? 1.0f : v;
}

__global__ void kTk(const float* __restrict__ adj, const float* __restrict__ masks,
                    const float* __restrict__ Us, float* __restrict__ t8) {
  int k = blockIdx.y;
  int i = blockIdx.x*16 + (threadIdx.x >> 4);
  int r = threadIdx.x & 15;
  const float* arow = adj + (u64)i*2048;
  const float* mrow = masks + ((u64)k*2048 + i)*2048;
  const float* uk = Us + (u64)k*2048*16 + r;
  float acc = 0.f;
  for (int j = 0; j < 2048; ++j) acc += arow[j]*mrow[j]*uk[(u64)j*16];
  t8[((u64)k*2048 + i)*16 + r] = acc;
}

__global__ void kAlpha(const float* alphas, float* alpha) {
  if (threadIdx.x == 0 && blockIdx.x == 0) {
    float m = alphas[0];
    for (int k = 1; k < 8; ++k) m = fmaxf(m, alphas[k]);
    float e[8]; float s = 0.f;
    for (int k = 0; k < 8; ++k) { e[k] = expf(alphas[k] - m); s += e[k]; }
    for (int k = 0; k < 8; ++k) alpha[k] = e[k]/s;
  }
}

__global__ void kOutAdj(const float* __restrict__ adj, const float* __restrict__ masks,
                        const float* __restrict__ Vs, const float* __restrict__ t8,
                        const float* __restrict__ alpha, float* __restrict__ oadj,
                        float* __restrict__ out0) {
  __shared__ float tS[8][16][16];
  __shared__ float vS[8][16][16];
  int j0 = blockIdx.x*16, i0 = blockIdx.y*16;
  int tid = threadIdx.x;
  for (int idx = tid; idx < 2048; idx += 256) {
    int k = idx >> 8, rem = idx & 255, row = rem >> 4, r = rem & 15;
    tS[k][row][r] = t8[((u64)k*2048 + i0 + row)*16 + r];
    vS[k][row][r] = Vs[((u64)k*2048 + j0 + row)*16 + r];
  }
  __syncthreads();
  int ii = tid >> 4, jj = tid & 15;
  int i = i0 + ii, j = j0 + jj;
  float corr = 0.f;
  for (int k = 0; k < 8; ++k) {
    float m = masks[((u64)k*2048 + i)*2048 + j];
    float dv = 0.f;
    #pragma unroll
    for (int r = 0; r < 16; ++r) dv += tS[k][ii][r]*vS[k][jj][r];
    corr += alpha[k]*m*dv;
  }
  float val = adj[(u64)i*2048 + j] + corr;
  oadj[(u64)i*2048 + j] = val;
  out0[(u64)i*2048 + j] = val;
}

__global__ void kFinal(const float* __restrict__ C, float* __restrict__ out1) {
  int gid = blockIdx.x*256 + threadIdx.x;
  if (gid >= 2048*2048) return;
  int i = gid >> 11, j = gid & 2047;
  float v;
  if (i == j) v = 1.0f;
  else v = 0.5f*(C[gid] + C[(u64)j*2048 + i]);
  out1[gid] = fabsf(v);
}

// ================= host =================

extern "C" void kernel_launch(void* const* d_in, const int* in_sizes, int n_in,
                              void* d_out, int out_size, void* d_ws, size_t ws_size,
                              hipStream_t stream) {
  const float* A      = (const float*)d_in[0];
  const float* X      = (const float*)d_in[1];
  const float* W      = (const float*)d_in[2];
  const float* Us     = (const float*)d_in[3];
  const float* Vs     = (const float*)d_in[4];
  const float* alphas = (const float*)d_in[5];
  const float* masks  = (const float*)d_in[6];

  char* ws = (char*)d_ws;
  double* A64  = (double*)(ws + OFF_A64);
  float*  Vt   = (float*) (ws + OFF_VT);
  double* tau  = (double*)(ws + OFF_TAU);
  double* d64  = (double*)(ws + OFF_D64);
  double* e64  = (double*)(ws + OFF_E64);
  double* diagP = (double*)(ws + OFF_XA);
  unsigned* flags = (unsigned*)(ws + OFF_XB);
  double* y1a  = (double*)(ws + OFF_Y1A);
  double* y1b  = (double*)(ws + OFF_Y1B);
  double* y2a  = (double*)(ws + OFF_Y2A);
  double* y2b  = (double*)(ws + OFF_Y2B);
  double* SCDB = (double*)(ws + OFF_SCDB);
  int*    SCIB = (int*)   (ws + OFF_SCIB);
  int*    KNB  = (int*)   (ws + OFF_KNB);
  double* KNDB = (double*)(ws + OFF_KNDB);
  float*  ALPH = (float*) (ws + OFF_ALPHA);
  float*  Qa   = (float*) (ws + OFF_QA);
  float*  Qb   = (float*) (ws + OFF_QB);
  float*  Shat = (float*) (ws + OFF_SHAT);
  float*  Wc   = (float*) (ws + OFF_WC);
  float*  M1   = (float*) (ws + OFF_M1);
  float*  T8   = (float*) (ws + OFF_T8);
  float*  ADJ  = (float*) (ws + OFF_ADJ);
  float*  OADJ = (float*) (ws + OFF_OADJ);
  float*  CB   = (float*) (ws + OFF_CBUF);

  float* out0 = (float*)d_out;                 // reference outputs are float32
  float* out1 = out0 + (u64)2048*2048;

  // --- tridiagonalization: 1 persistent launch (64 blocks), flag barrier ---
  hipMemsetAsync(ws + OFF_XB, 0, 4096, stream);    // zero 64 padded barrier flags
  kCopyA<<<4096, 256, 0, stream>>>(A, A64);
  {
    void* kargs[] = { (void*)&A64, (void*)&y1a, (void*)&y1b, (void*)&y2a, (void*)&y2b,
                      (void*)&diagP, (void*)&flags,
                      (void*)&tau, (void*)&e64, (void*)&d64, (void*)&Vt };
    hipLaunchCooperativeKernel((void*)kTriDiag, dim3(TD_NBLK), dim3(1024), kargs, 0, stream);
  }

  // --- D&C: leaves, batched merges (cuts folded into kTriDiag tail) ---
  hipMemsetAsync(Qa, 0, (size_t)4*MBYTE, stream);
  kLeaf<<<64, 64, 0, stream>>>(d64, e64, Qa);

  for (int lvl = 0; lvl < 6; ++lvl) {
    int bs = 16 << lvl;
    int n = 2*bs;
    int cnt = 1024/n;
    kDeflateB<<<cnt, 1024, 0, stream>>>(Qa, d64, e64, SCDB, SCIB, KNB, KNDB, bs);
    kSecularB<<<dim3((n + 3)/4, cnt), 256, 0, stream>>>(SCDB, KNB, KNDB);
    kZhatB<<<dim3((n + 63)/64, cnt), 64, 0, stream>>>(SCDB, KNB);
    kSortPermB<<<cnt, 1024, 0, stream>>>(SCDB, SCIB, KNB, d64, bs);
    kSvecNormB<<<dim3(n, cnt), 256, 0, stream>>>(Shat, SCDB, KNB, bs);
    kGatherB<<<dim3((n*n + 255)/256, cnt), 256, 0, stream>>>(Qa, Qb, SCIB, KNB, bs);
    kGemmMergeB<<<dim3(n/16, n/16, cnt), dim3(16, 16), 0, stream>>>(Qb, Shat, Qa, SCIB, KNB, bs);
    kScatterDeflB<<<dim3((n*n + 255)/256, cnt), 256, 0, stream>>>(Qb, Qa, SCIB, KNB, bs);
  }

  // --- back-transform: Qa = U (eigenvectors of A, ascending) ---
  kBackx<<<64, 256, 0, stream>>>(Qa, Vt, tau);

  // --- downstream pipeline ---
  kWc<<<8192, 256, 0, stream>>>(W, Wc);
  // M1 = U^T @ X  (1024 x 2048)
  gemm_f32<1,0><<<dim3(16, 8), 256, 0, stream>>>(Qa, X, M1, 1024, 2048, 1024, 1024, 2048, 2048);
  // f_d = Wc @ M1 (2048 x 2048) -> ADJ
  gemm_f32<0,0><<<dim3(16, 16), 256, 0, stream>>>(Wc, M1, ADJ, 2048, 2048, 1024, 1024, 2048, 2048);
  kAbsDiag<<<16384, 256, 0, stream>>>(ADJ);
  kTk<<<dim3(128, 8), 256, 0, stream>>>(ADJ, masks, Us, T8);
  kAlpha<<<1, 64, 0, stream>>>(alphas, ALPH);
  kOutAdj<<<dim3(128, 128), 256, 0, stream>>>(ADJ, masks, Vs, T8, ALPH, OADJ, out0);
  // C = out_adj @ out_adj^T
  gemm_f32<0,1><<<dim3(16, 16), 256, 0, stream>>>(OADJ, OADJ, CB, 2048, 2048, 2048, 2048, 2048, 2048);
  kFinal<<<16384, 256, 0, stream>>>(CB, out1);
}

// Round 6
// 16781.531 us; speedup vs baseline: 2.2834x; 1.2078x over previous
//
#include <hip/hip_runtime.h>
#include <hip/hip_bf16.h>

typedef unsigned long long u64;

#define MBYTE (1ull << 20)

// ---------------- workspace layout (bytes) ----------------
static const size_t OFF_A64   = 0;                    // 1024^2 f64 (8MB)
static const size_t OFF_VT    = 8*MBYTE;              // 1024^2 f32 (4MB) reflectors transposed
static const size_t OFF_TAU   = 12*MBYTE;             // 1024 f64
static const size_t OFF_D64   = 12*MBYTE +  8192;
static const size_t OFF_E64   = 12*MBYTE + 16384;
static const size_t OFF_XB    = 12*MBYTE + 24576;     // barrier flags (64 x 64B-padded u32)
static const size_t OFF_Y2B   = 12*MBYTE + 32768;     // y2 pong
static const size_t OFF_Y1B   = 12*MBYTE + 40960;     // y1 pong
static const size_t OFF_XA    = 12*MBYTE + 49152;     // diag publication (1024 f64)
static const size_t OFF_Y1A   = 12*MBYTE + 57344;     // y1 ping
static const size_t OFF_Y2A   = 12*MBYTE + 65536;     // y2 ping
static const size_t OFF_QA    = 13*MBYTE;             // 4MB f32 (D&C Q, later U)
static const size_t OFF_QB    = 17*MBYTE;             // 4MB f32
static const size_t OFF_SHAT  = 21*MBYTE;             // 4MB f32
static const size_t OFF_WC    = 25*MBYTE;             // 8MB f32; D&C scratch, then WY scratch
static const size_t OFF_M1    = 33*MBYTE;             // 8MB f32
static const size_t OFF_T8    = 33*MBYTE;             // 2MB f32 (reuses M1, dead by then)
static const size_t OFF_ALPHA = 35*MBYTE + 512*1024;  // float[8] (dead region)
static const size_t OFF_ADJ   = 41*MBYTE;             // 16MB f32
static const size_t OFF_OADJ  = 17*MBYTE;             // 16MB f32 (reuses QB/SHAT, dead)
static const size_t OFF_CBUF  = 0;                    // 16MB f32 (reuses A64/VT/QA, dead)

// batched D&C scratch inside the (dead-during-D&C) WC region
static const size_t SCD_STRIDE = 9216;   // doubles per merge
static const size_t SCI_STRIDE = 6144;   // ints per merge
static const size_t OFF_SCDB  = OFF_WC;                       // 32*9216*8 = 2359296
static const size_t OFF_SCIB  = OFF_WC + 2359296;             // 32*6144*4 = 786432
static const size_t OFF_KNB   = OFF_WC + 2359296 + 786432;    // 32*8 ints
static const size_t OFF_KNDB  = OFF_WC + 2359296 + 786432 + 2048; // 32*4 dbl

// WY back-transform scratch (reuses WC region, dead after D&C)
static const size_t OFF_WYW   = OFF_WC;               // 64x1024 f64 (512KB)
static const size_t OFF_WYTW  = OFF_WC + 524288;      // 64x1024 f64 (512KB)
static const size_t OFF_WYG   = OFF_WC + 1048576;     // 64x64 f64 (32KB)

// ================= tridiagonalization (ssytd2-faithful, lower, f64) =================
// PERSISTENT kernel, 64 blocks x 1024 threads (round-3/5 geometry).

__global__ void kCopyA(const float* __restrict__ A, double* __restrict__ A64) {
  int gid = blockIdx.x*256 + threadIdx.x;
  if (gid < 1024*1024) A64[gid] = (double)A[gid];
}

__device__ __forceinline__ double agLoadD(const double* p) {
  return __hip_atomic_load(p, __ATOMIC_RELAXED, __HIP_MEMORY_SCOPE_AGENT);
}
__device__ __forceinline__ void agStoreD(double* p, double v) {
  __hip_atomic_store(p, v, __ATOMIC_RELAXED, __HIP_MEMORY_SCOPE_AGENT);
}

#define TD_NBLK 64

__global__ __launch_bounds__(1024) void kTriDiag(
    double* __restrict__ A64,
    double* __restrict__ y1A, double* __restrict__ y1B,
    double* __restrict__ y2A, double* __restrict__ y2B,
    double* __restrict__ diagP, unsigned* __restrict__ flags,
    double* __restrict__ tauv, double* __restrict__ e64, double* __restrict__ d64,
    float* __restrict__ Vt) {
  __shared__ double xL[1024], vL[1024], wL[1024], y1L[1024], y2L[1024];
  __shared__ double red[4];
  __shared__ double sS[4];
  int tid = threadIdx.x;
  int bid = blockIdx.x;
  bool w0 = (bid == 0);
  int lane = tid & 63, wave = tid >> 6;   // 16 waves
  int myRow = wave*TD_NBLK + bid;         // bijective 0..1023

  double dg = 0.0;                        // diag prefetch register (thread 0 of block 0)

  for (int i = 0; i <= 1023; ++i) {
    const double* y1in = (((i-1)&1) != 0) ? y1B : y1A;   // only used for i>=1
    const double* y2in = (((i-1)&1) != 0) ? y2B : y2A;
    double* y1out = ((i&1) != 0) ? y1B : y1A;
    double* y2out = ((i&1) != 0) ? y2B : y2A;

    if (i == 0) {
      if (tid < 256) {
        for (int c = tid; c < 1024; c += 256) { vL[c] = 0.0; wL[c] = 0.0; }
        for (int c = 1 + tid; c < 1024; c += 256) xL[c] = A64[(u64)c*1024];
        if (w0 && tid == 0) d64[0] = A64[0];
      }
      __syncthreads();
    } else {
      int j = i - 1;                       // reflector being finalized
      double sy1 = agLoadD(&y1in[tid]);
      double sy2 = agLoadD(&y2in[tid]);
      if (w0 && tid == 0) dg = agLoadD(&diagP[i]);
      double acc = 0.0;
      if (tid < 256) {
        for (int c = i + 1 + tid; c < 1024; c += 256) { double v = xL[c]; acc += v*v; }
        for (int off = 32; off > 0; off >>= 1) acc += __shfl_xor(acc, off, 64);
      }
      y1L[tid] = sy1; y2L[tid] = sy2;
      if (tid < 256 && lane == 0) red[wave] = acc;
      __syncthreads();                                   // S1
      if (tid == 0) {
        double xn2 = red[0] + red[1] + red[2] + red[3];
        double alpha = xL[i];
        double tv, sc;
        if (xn2 == 0.0) { tv = 0.0; if (w0) e64[j] = alpha; sc = 0.0; }
        else {
          double beta = (alpha >= 0.0) ? -sqrt(alpha*alpha + xn2) : sqrt(alpha*alpha + xn2);
          tv = (beta - alpha)/beta;
          if (w0) e64[j] = beta;
          sc = 1.0/(alpha - beta);
        }
        if (w0) tauv[j] = tv;
        sS[0] = sc; sS[1] = tv;
        vL[i] = 1.0;
        if (w0) Vt[(u64)j*1024 + i] = 1.0f;
      }
      __syncthreads();                                   // S2
      if (tid < 256) {
        double sc = sS[0], tv = sS[1];
        double acc2 = 0.0;
        for (int r = i + tid; r < 1024; r += 256) {
          double v;
          if (r == i) v = 1.0;
          else {
            v = xL[r]*sc;
            vL[r] = v;
            if (w0) Vt[(u64)j*1024 + r] = (float)v;
          }
          double P = tv*(y1L[r] + sc*y2L[r]);
          wL[r] = P;
          acc2 += P*v;
        }
        for (int off = 32; off > 0; off >>= 1) acc2 += __shfl_xor(acc2, off, 64);
        if (lane == 0) red[wave] = acc2;
      }
      __syncthreads();                                   // S3
      if (tid == 0) {
        double coef = 0.5*sS[1]*(red[0] + red[1] + red[2] + red[3]);
        double wi = wL[i] - coef;
        sS[2] = coef; sS[3] = wi;
        if (w0) d64[i] = dg - 2.0*wi;
      }
      __syncthreads();                                   // S4
      if (tid < 256) {
        double coef = sS[2], wi = sS[3];
        for (int r = i + tid; r < 1024; r += 256) {
          double wcr = wL[r] - coef*vL[r];
          wL[r] = wcr;
          if (r > i) xL[r] = y1L[r] - vL[r]*wi - wcr;
        }
      }
      __syncthreads();                                   // S5
    }
    // ---- Phase B: rank-2 apply to OWN row fused with y1/y2 = A'*x ----
    if (i <= 1022) {
      int r = myRow;
      if (r >= i + 1) {
        double vr = vL[r], wr = wL[r];
        double* Arow = A64 + (u64)r*1024;
        double acc = 0.0, y1v = 0.0;
        for (int c = i + 1 + lane; c < 1024; c += 64) {
          double a = Arow[c] - vr*wL[c] - wr*vL[c];
          Arow[c] = a;
          if (c == r) agStoreD(&diagP[r], a);      // publish diagonal
          if (c == i + 1) y1v = a; else acc += a*xL[c];
        }
        for (int off = 32; off > 0; off >>= 1) acc += __shfl_down(acc, off, 64);
        if (lane == 0) { agStoreD(&y1out[r], y1v); agStoreD(&y2out[r], acc); }
      }
      __syncthreads();                                   // S6
      unsigned tgt = (unsigned)(i + 1);
      if (tid == 0)
        __hip_atomic_store(&flags[bid*16], tgt, __ATOMIC_RELEASE, __HIP_MEMORY_SCOPE_AGENT);
      if (tid < TD_NBLK) {
        for (;;) {
          unsigned v = __hip_atomic_load(&flags[tid*16], __ATOMIC_ACQUIRE, __HIP_MEMORY_SCOPE_AGENT);
          if (__all(v >= tgt)) break;
          __builtin_amdgcn_s_sleep(2);
        }
      }
      __syncthreads();                                   // S7
    }
  }
  // folded kCuts
  if (w0 && tid == 0) {
    for (int c = 16; c < 1024; c += 16) {
      double ae = fabs(e64[c-1]);
      d64[c-1] -= ae;
      d64[c]   -= ae;
    }
  }
}

// ================= ssteqr (leaves, n=16, COMPZ='I') =================

__device__ void slartg_(double f, double g, double* cs, double* sn, double* r) {
  if (g == 0.0) { *cs = 1.0; *sn = 0.0; *r = f; }
  else if (f == 0.0) { *cs = 0.0; *sn = (g >= 0.0) ? 1.0 : -1.0; *r = fabs(g); }
  else {
    double d = sqrt(f*f + g*g);
    *cs = fabs(f)/d;
    *r = (f >= 0.0) ? d : -d;
    *sn = g / (*r);
  }
}

__device__ void slaev2_(double a, double b, double c, double* rt1, double* rt2,
                        double* cs1, double* sn1) {
  double sm = a + c, df = a - c, adf = fabs(df), tb = b + b, ab = fabs(tb);
  double acmx, acmn;
  if (fabs(a) > fabs(c)) { acmx = a; acmn = c; } else { acmx = c; acmn = a; }
  double rt;
  if (adf > ab) rt = adf*sqrt(1.0 + (ab/adf)*(ab/adf));
  else if (adf < ab) rt = ab*sqrt(1.0 + (adf/ab)*(adf/ab));
  else rt = ab*sqrt(2.0);
  int sgn1;
  if (sm < 0.0) { *rt1 = 0.5*(sm - rt); sgn1 = -1; *rt2 = (acmx / *rt1)*acmn - (b / *rt1)*b; }
  else if (sm > 0.0) { *rt1 = 0.5*(sm + rt); sgn1 = 1; *rt2 = (acmx / *rt1)*acmn - (b / *rt1)*b; }
  else { *rt1 = 0.5*rt; *rt2 = -0.5*rt; sgn1 = 1; }
  int sgn2; double cs;
  if (df >= 0.0) { cs = df + rt; sgn2 = 1; } else { cs = df - rt; sgn2 = -1; }
  double acs = fabs(cs);
  if (acs > ab) { double ct = -tb/cs; *sn1 = 1.0/sqrt(1.0 + ct*ct); *cs1 = ct*(*sn1); }
  else {
    if (ab == 0.0) { *cs1 = 1.0; *sn1 = 0.0; }
    else { double tn = -cs/tb; *cs1 = 1.0/sqrt(1.0 + tn*tn); *sn1 = tn*(*cs1); }
  }
  if (sgn1 == sgn2) { double tn = *cs1; *cs1 = -(*sn1); *sn1 = tn; }
}

__device__ void steqr16_(double* d, double* e, double* z, double* wc, double* ws_) {
  const int n = 16;
  const double eps = 5.9604644775390625e-08;
  const double eps2 = eps*eps;
  const double safmin = 1.1754943508222875e-38;
  int jtot = 0; const int nmaxit = n*30;
  int l1 = 0;
  for (int outer = 0; outer < 200; ++outer) {
    if (l1 > n-1) break;
    if (l1 > 0) e[l1-1] = 0.0;
    int m = l1;
    for (; m <= n-2; ++m) {
      double tst = fabs(e[m]);
      if (tst == 0.0) break;
      if (tst <= (sqrt(fabs(d[m]))*sqrt(fabs(d[m+1])))*eps) { e[m] = 0.0; break; }
    }
    int l = l1, lend = m;
    l1 = m + 1;
    if (lend == l) continue;
    if (fabs(d[lend]) < fabs(d[l])) { int t = l; l = lend; lend = t; }
    if (lend > l) {
      for (int it = 0; it < 800; ++it) {
        int mm = lend;
        if (l != lend) {
          for (mm = l; mm <= lend-1; ++mm) {
            double tst = e[mm]*e[mm];
            if (tst <= eps2*fabs(d[mm])*fabs(d[mm+1]) + safmin) break;
          }
        }
        if (mm < lend) e[mm] = 0.0;
        double p = d[l];
        if (mm == l) { d[l] = p; ++l; if (l <= lend) continue; break; }
        if (mm == l+1) {
          double rt1, rt2, c2, s2;
          slaev2_(d[l], e[l], d[l+1], &rt1, &rt2, &c2, &s2);
          for (int r = 0; r < n; ++r) {
            double t = z[r*16 + l + 1];
            z[r*16 + l + 1] = c2*t - s2*z[r*16 + l];
            z[r*16 + l]     = s2*t + c2*z[r*16 + l];
          }
          d[l] = rt1; d[l+1] = rt2; e[l] = 0.0;
          l += 2; if (l <= lend) continue; break;
        }
        if (jtot == nmaxit) break;
        ++jtot;
        double g = (d[l+1] - p)/(2.0*e[l]);
        double r_ = sqrt(g*g + 1.0);
        g = d[mm] - p + e[l]/(g + ((g >= 0.0) ? r_ : -r_));
        double s = 1.0, c = 1.0;
        p = 0.0;
        for (int i = mm-1; i >= l; --i) {
          double f = s*e[i], b = c*e[i];
          double cs, sn, rr;
          slartg_(g, f, &cs, &sn, &rr);
          c = cs; s = sn;
          if (i != mm-1) e[i+1] = rr;
          g = d[i+1] - p;
          rr = (d[i] - g)*s + 2.0*c*b;
          p = s*rr;
          d[i+1] = g + p;
          g = c*rr - b;
          wc[i] = c; ws_[i] = -s;
        }
        for (int jj = mm-1; jj >= l; --jj) {
          double cs = wc[jj], sn = ws_[jj];
          for (int r = 0; r < n; ++r) {
            double t = z[r*16 + jj + 1];
            z[r*16 + jj + 1] = cs*t - sn*z[r*16 + jj];
            z[r*16 + jj]     = sn*t + cs*z[r*16 + jj];
          }
        }
        d[l] -= p;
        e[l] = g;
      }
    } else {
      for (int it = 0; it < 800; ++it) {
        int mm = lend;
        if (l != lend) {
          for (mm = l; mm >= lend+1; --mm) {
            double tst = e[mm-1]*e[mm-1];
            if (tst <= eps2*fabs(d[mm])*fabs(d[mm-1]) + safmin) break;
          }
        }
        if (mm > lend) e[mm-1] = 0.0;
        double p = d[l];
        if (mm == l) { d[l] = p; --l; if (l >= lend) continue; break; }
        if (mm == l-1) {
          double rt1, rt2, c2, s2;
          slaev2_(d[l-1], e[l-1], d[l], &rt1, &rt2, &c2, &s2);
          for (int r = 0; r < n; ++r) {
            double t = z[r*16 + l];
            z[r*16 + l]     = c2*t - s2*z[r*16 + l - 1];
            z[r*16 + l - 1] = s2*t + c2*z[r*16 + l - 1];
          }
          d[l-1] = rt1; d[l] = rt2; e[l-1] = 0.0;
          l -= 2; if (l >= lend) continue; break;
        }
        if (jtot == nmaxit) break;
        ++jtot;
        double g = (d[l-1] - p)/(2.0*e[l-1]);
        double r_ = sqrt(g*g + 1.0);
        g = d[mm] - p + e[l-1]/(g + ((g >= 0.0) ? r_ : -r_));
        double s = 1.0, c = 1.0;
        p = 0.0;
        for (int i = mm; i <= l-1; ++i) {
          double f = s*e[i], b = c*e[i];
          double cs, sn, rr;
          slartg_(g, f, &cs, &sn, &rr);
          c = cs; s = sn;
          if (i != mm) e[i-1] = rr;
          g = d[i] - p;
          rr = (d[i+1] - g)*s + 2.0*c*b;
          p = s*rr;
          d[i] = g + p;
          g = c*rr - b;
          wc[i] = c; ws_[i] = s;
        }
        for (int jj = mm; jj <= l-1; ++jj) {
          double cs = wc[jj], sn = ws_[jj];
          for (int r = 0; r < n; ++r) {
            double t = z[r*16 + jj + 1];
            z[r*16 + jj + 1] = cs*t - sn*z[r*16 + jj];
            z[r*16 + jj]     = sn*t + cs*z[r*16 + jj];
          }
        }
        d[l] -= p;
        e[l-1] = g;
      }
    }
  }
  for (int ii = 1; ii <= n-1; ++ii) {
    int i = ii - 1, k = i;
    double p = d[i];
    for (int j = ii; j <= n-1; ++j) if (d[j] < p) { k = j; p = d[j]; }
    if (k != i) {
      d[k] = d[i]; d[i] = p;
      for (int r = 0; r < n; ++r) { double t = z[r*16 + i]; z[r*16 + i] = z[r*16 + k]; z[r*16 + k] = t; }
    }
  }
}

__global__ void kLeaf(double* d64, const double* e64, float* Qa) {
  __shared__ double dd[16], ed[16], zd[256], wk1[16], wk2[16];
  int leaf = blockIdx.x, lo = leaf*16, tid = threadIdx.x;
  for (int idx = tid; idx < 256; idx += 64) zd[idx] = ((idx/16) == (idx%16)) ? 1.0 : 0.0;
  if (tid < 16) { dd[tid] = d64[lo + tid]; ed[tid] = (tid < 15) ? e64[lo + tid] : 0.0; }
  __syncthreads();
  if (tid == 0) steqr16_(dd, ed, zd, wk1, wk2);
  __syncthreads();
  for (int idx = tid; idx < 256; idx += 64) {
    int r = idx/16, c = idx%16;
    Qa[(u64)(lo + r)*1024 + lo + c] = (float)zd[idx];
  }
  if (tid < 16) d64[lo + tid] = dd[tid];
}

// ================= batched D&C merge =================

__global__ __launch_bounds__(1024) void kDeflateB(float* __restrict__ Qa,
      const double* __restrict__ d64, const double* __restrict__ e64,
      double* scdB, int* sciB, int* knB, double* kndB, int bs) {
  __shared__ double zL[1024], dlocL[1024], redD[1024];
  __shared__ double rcL[1024], rsL[1024];
  __shared__ int sIdxL[1024], rpqL[1024];
  __shared__ double sSc[4];
  __shared__ int sKn[4];
  int mg = blockIdx.x;
  int n1 = bs, n = 2*bs, lo = mg*n;
  double* scd = scdB + (u64)mg*SCD_STRIDE;
  int*    sci = sciB + (u64)mg*SCI_STRIDE;
  int* kn = knB + mg*8;
  double* knd = kndB + mg*4;
  int tid = threadIdx.x;
  if (tid == 0) sSc[0] = e64[lo + n1 - 1];
  __syncthreads();
  double rho_in = sSc[0];
  const double invs2 = 0.70710678118654752440;
  if (tid < n) {
    int row = (tid < n1) ? (lo + n1 - 1) : (lo + n1);
    double s = (rho_in < 0.0 && tid >= n1) ? -invs2 : invs2;
    zL[tid] = (double)Qa[(u64)row*1024 + lo + tid] * s;
    dlocL[tid] = d64[lo + tid];
  }
  __syncthreads();
  if (tid < n) {
    int pos; double key = dlocL[tid];
    if (tid < n1) {
      int loB = 0, hiB = n - n1;
      while (loB < hiB) { int mid = (loB+hiB)>>1; if (dlocL[n1+mid] < key) loB = mid+1; else hiB = mid; }
      pos = tid + loB;
    } else {
      int loA = 0, hiA = n1;
      while (loA < hiA) { int mid = (loA+hiA)>>1; if (dlocL[mid] <= key) loA = mid+1; else hiA = mid; }
      pos = (tid - n1) + loA;
    }
    sIdxL[pos] = tid;
  }
  redD[tid] = (tid < n) ? fabs(zL[tid]) : 0.0;
  __syncthreads();
  for (int s = 512; s > 0; s >>= 1) { if (tid < s) redD[tid] = fmax(redD[tid], redD[tid+s]); __syncthreads(); }
  if (tid == 0) sSc[1] = redD[0];
  __syncthreads();
  redD[tid] = (tid < n) ? fabs(dlocL[tid]) : 0.0;
  __syncthreads();
  for (int s = 512; s > 0; s >>= 1) { if (tid < s) redD[tid] = fmax(redD[tid], redD[tid+s]); __syncthreads(); }
  if (tid == 0) {
    double zmax = sSc[1], dmax = redD[0];
    double rho = fabs(2.0*rho_in);
    double tol = 8.0*5.9604644775390625e-8*fmax(dmax, zmax);
    double* dlG = scd + 1024;
    double* wmG = scd + 2048;
    double* dvalG = scd + 7168;
    int* permG = sci;
    int* deflG = sci + 1024;
    int K = 0, nrot = 0, nd = 0; double sw2 = 0.0;
    if (rho*zmax <= tol) {
      for (int pos = 0; pos < n; ++pos) { int c = sIdxL[pos]; deflG[nd] = c; dvalG[nd] = dlocL[c]; nd++; }
    } else {
      int pj = -1, jpos = 0;
      for (; jpos < n; ++jpos) {
        int nj = sIdxL[jpos];
        if (rho*fabs(zL[nj]) <= tol) { deflG[nd] = nj; dvalG[nd] = dlocL[nj]; nd++; }
        else { pj = nj; break; }
      }
      for (++jpos; jpos < n; ++jpos) {
        int nj = sIdxL[jpos];
        if (rho*fabs(zL[nj]) <= tol) { deflG[nd] = nj; dvalG[nd] = dlocL[nj]; nd++; continue; }
        double s_ = zL[pj], c_ = zL[nj];
        double tu = sqrt(c_*c_ + s_*s_);
        double tdif = dlocL[nj] - dlocL[pj];
        c_ /= tu; s_ = -s_/tu;
        if (fabs(tdif*c_*s_) <= tol) {
          zL[nj] = tu; zL[pj] = 0.0;
          rpqL[nrot] = (pj << 16) | nj; rcL[nrot] = c_; rsL[nrot] = s_; nrot++;
          double t1 = dlocL[pj]*c_*c_ + dlocL[nj]*s_*s_;
          dlocL[nj] = dlocL[pj]*s_*s_ + dlocL[nj]*c_*c_;
          dlocL[pj] = t1;
          deflG[nd] = pj; dvalG[nd] = t1; nd++;
          pj = nj;
        } else {
          permG[K] = pj; dlG[K] = dlocL[pj]; wmG[K] = zL[pj]; sw2 += zL[pj]*zL[pj]; K++;
          pj = nj;
        }
      }
      permG[K] = pj; dlG[K] = dlocL[pj]; wmG[K] = zL[pj]; sw2 += zL[pj]*zL[pj]; K++;
    }
    sKn[1] = nrot;
    kn[0] = K; kn[1] = nrot; kn[2] = nd;
    knd[0] = rho; knd[1] = sw2;
  }
  __syncthreads();
  int nrot = sKn[1];
  if (tid < n && nrot > 0) {
    u64 row = (u64)(lo + tid)*1024;
    for (int t = 0; t < nrot; ++t) {
      int pq = rpqL[t];
      int p = lo + (pq >> 16), q = lo + (pq & 0xffff);
      double c = rcL[t], s = rsL[t];
      double x = (double)Qa[row + p], y = (double)Qa[row + q];
      Qa[row + p] = (float)(c*x + s*y);
      Qa[row + q] = (float)(c*y - s*x);
    }
  }
}

__global__ __launch_bounds__(256) void kSecularB(double* scdB, const int* knB, const double* kndB) {
  __shared__ double dlS[1024], wmS[1024];
  int mg = blockIdx.y;
  double* scd = scdB + (u64)mg*SCD_STRIDE;
  const int* kn = knB + mg*8;
  const double* knd = kndB + mg*4;
  int K = kn[0];
  int tid = threadIdx.x;
  for (int j = tid; j < K; j += 256) { dlS[j] = scd[1024 + j]; wmS[j] = scd[2048 + j]; }
  __syncthreads();
  int wave = tid >> 6, lane = tid & 63;
  int i = blockIdx.x*4 + wave;
  if (i >= K) return;
  double rho = knd[0], sw2 = knd[1];
  double di = dlS[i];
  double hi = (i < K-1) ? (dlS[i+1] - di) : (rho*sw2*(1.0 + 1e-12) + 1e-300);
  double lo_ = 0.0;
  for (int it = 0; it < 100; ++it) {
    double mid = 0.5*(lo_ + hi);
    double g = 0.0;
    for (int j = lane; j < K; j += 64) { double w = wmS[j]; g += w*w/((dlS[j] - di) - mid); }
    for (int off = 32; off > 0; off >>= 1) g += __shfl_xor(g, off);
    g = 1.0 + rho*g;
    if (g < 0.0) lo_ = mid; else hi = mid;
  }
  scd[3072 + i] = 0.5*(lo_ + hi);
}

__global__ void kZhatB(double* scdB, const int* knB) {
  int mg = blockIdx.y;
  double* scd = scdB + (u64)mg*SCD_STRIDE;
  int K = (knB + mg*8)[0];
  int j = blockIdx.x*64 + threadIdx.x;
  if (j >= K) return;
  const double* dl = scd + 1024;
  const double* wm = scd + 2048;
  const double* mu = scd + 3072;
  double dj = dl[j];
  double prod = mu[j];
  for (int i2 = 0; i2 < K; ++i2) {
    if (i2 == j) continue;
    double dd = dl[i2] - dj;
    prod *= (dd + mu[i2]) / dd;
  }
  prod = fabs(prod);
  scd[4096 + j] = (wm[j] >= 0.0) ? sqrt(prod) : -sqrt(prod);
}

__global__ __launch_bounds__(1024) void kSortPermB(double* scdB, int* sciB, const int* knB,
                                                   double* d64, int bs) {
  __shared__ double sv[1024];
  __shared__ int si[1024];
  int mg = blockIdx.x;
  int n = 2*bs, lo = mg*n;
  double* scd = scdB + (u64)mg*SCD_STRIDE;
  int* sci = sciB + (u64)mg*SCI_STRIDE;
  int K = (knB + mg*8)[0];
  int tid = threadIdx.x;
  const double* dl = scd + 1024;
  const double* mu = scd + 3072;
  const double* dval = scd + 7168;
  double v;
  if (tid < K) v = dl[tid] + mu[tid];
  else if (tid < n) v = dval[tid - K];
  else v = 1e300;
  sv[tid] = v; si[tid] = tid;
  __syncthreads();
  for (int k = 2; k <= 1024; k <<= 1) {
    for (int j = k >> 1; j > 0; j >>= 1) {
      int ixj = tid ^ j;
      if (ixj > tid) {
        bool up = ((tid & k) == 0);
        double a = sv[tid], b = sv[ixj];
        int ia = si[tid], ib = si[ixj];
        bool agtb = (a > b) || (a == b && ia > ib);
        if (up ? agtb : !agtb) { sv[tid] = b; sv[ixj] = a; si[tid] = ib; si[ixj] = ia; }
      }
      __syncthreads();
    }
  }
  if (tid < n) {
    int s = si[tid];
    if (s < K) sci[4096 + s] = tid; else sci[5120 + s - K] = tid;
    d64[lo + tid] = sv[tid];
  }
}

__global__ void kSvecNormB(float* __restrict__ Shat, const double* scdB, const int* knB, int bs) {
  int mg = blockIdx.y;
  int n = 2*bs, lo = mg*n;
  const double* scd = scdB + (u64)mg*SCD_STRIDE;
  int K = (knB + mg*8)[0];
  int i = blockIdx.x;
  if (i >= K) return;
  const double* dl = scd + 1024;
  const double* mu = scd + 3072;
  const double* zh = scd + 4096;
  __shared__ double red[256];
  int tid = threadIdx.x;
  double di = dl[i], m = mu[i];
  double acc = 0.0;
  for (int j = tid; j < K; j += 256) {
    double v = zh[j]/((dl[j] - di) - m);
    acc += v*v;
  }
  red[tid] = acc; __syncthreads();
  for (int s = 128; s > 0; s >>= 1) { if (tid < s) red[tid] += red[tid+s]; __syncthreads(); }
  double inv = 1.0/sqrt(red[0]);
  for (int j = tid; j < K; j += 256) {
    double v = zh[j]/((dl[j] - di) - m);
    Shat[(u64)j*1024 + lo + i] = (float)(v*inv);
  }
}

__global__ void kGatherB(const float* Qa, float* Qb, const int* sciB, const int* knB, int bs) {
  int mg = blockIdx.y;
  int n = 2*bs, lo = mg*n;
  const int* sci = sciB + (u64)mg*SCI_STRIDE;
  int K = (knB + mg*8)[0];
  int gid = blockIdx.x*256 + threadIdx.x;
  if (gid >= n*n) return;
  int p = gid % n, r = gid / n;
  int src = (p < K) ? sci[p] : sci[1024 + p - K];
  Qb[(u64)(lo + r)*1024 + p] = Qa[(u64)(lo + r)*1024 + lo + src];
}

__global__ void kGemmMergeB(const float* __restrict__ Qb, const float* __restrict__ Shat,
                            float* __restrict__ Qa, const int* sciB, const int* knB, int bs) {
  __shared__ float As[16][17], Bs[16][17];
  int mg = blockIdx.z;
  int n = 2*bs, lo = mg*n;
  const int* sci = sciB + (u64)mg*SCI_STRIDE;
  int K = (knB + mg*8)[0];
  int tx = threadIdx.x, ty = threadIdx.y;
  int r0 = blockIdx.y*16, c0 = blockIdx.x*16;
  const int* rootpos = sci + 4096;
  float acc = 0.f;
  for (int k0 = 0; k0 < K; k0 += 16) {
    As[ty][tx] = (k0 + tx < K) ? Qb[(u64)(lo + r0 + ty)*1024 + k0 + tx] : 0.f;
    Bs[ty][tx] = (k0 + ty < K && c0 + tx < K) ? Shat[(u64)(k0 + ty)*1024 + lo + c0 + tx] : 0.f;
    __syncthreads();
    #pragma unroll
    for (int kk = 0; kk < 16; ++kk) acc += As[ty][kk]*Bs[kk][tx];
    __syncthreads();
  }
  int i = c0 + tx;
  if (i < K) Qa[(u64)(lo + r0 + ty)*1024 + lo + rootpos[i]] = acc;
}

__global__ void kScatterDeflB(const float* Qb, float* Qa, const int* sciB, const int* knB, int bs) {
  int mg = blockIdx.y;
  int n = 2*bs, lo = mg*n;
  const int* sci = sciB + (u64)mg*SCI_STRIDE;
  const int* kn = knB + mg*8;
  int gid = blockIdx.x*256 + threadIdx.x;
  if (gid >= n*n) return;
  int p = gid % n, r = gid / n;
  int K = kn[0], nd = kn[2];
  if (p < K || p - K >= nd) return;
  Qa[(u64)(lo + r)*1024 + lo + sci[5120 + p - K]] = Qb[(u64)(lo + r)*1024 + p];
}

// ================= back-transform: blocked compact-WY (larft/larfb) =================
// Q = H_0 H_1 ... H_1022.  Blocks of nb=64 reflectors:  P = I - V T V^T
// (LAPACK forward/columnwise).  Z <- P Z applied for i0 = 960, 896, ..., 0.
// v_j support: rows j+1..1023 (Vt[j][j+1]=1).  Vt lower triangle zero-filled once.
// All accumulation in f64.

__global__ void kVtZero(float* __restrict__ Vt) {
  int gid = blockIdx.x*256 + threadIdx.x;
  if (gid >= 1024*1024) return;
  int row = gid >> 10, col = gid & 1023;
  if (col <= row) Vt[gid] = 0.f;   // also fully zeroes unwritten row 1023
}

// blocks 0..15: W[j][c] = sum_r V[r][j]*Z[r][c]  (64 x 64-col tile each)
// block 16:     G[j1][j2] = sum_r V[r][j1]*V[r][j2]
__global__ __launch_bounds__(256) void kWyW(const float* __restrict__ Vt,
    const float* __restrict__ Qa, double* __restrict__ W, double* __restrict__ G,
    int i0, int rbeg) {
  __shared__ float sA[64][33];
  __shared__ float sB[32][65];
  int tid = threadIdx.x;
  int tx = tid & 15, ty = tid >> 4;
  if (blockIdx.x < 16) {
    int c0 = blockIdx.x*64;
    double acc[4][4];
    #pragma unroll
    for (int i = 0; i < 4; ++i)
      #pragma unroll
      for (int k = 0; k < 4; ++k) acc[i][k] = 0.0;
    for (int r0 = rbeg; r0 < 1024; r0 += 32) {
      #pragma unroll
      for (int k = 0; k < 8; ++k) {
        int e = tid + k*256;
        int j = e >> 5, rr = e & 31;
        int r = r0 + rr;
        sA[j][rr] = (r < 1024) ? Vt[(u64)(i0 + j)*1024 + r] : 0.f;
      }
      #pragma unroll
      for (int k = 0; k < 8; ++k) {
        int e = tid + k*256;
        int rr = e >> 6, cc = e & 63;
        int r = r0 + rr;
        sB[rr][cc] = (r < 1024) ? Qa[(u64)r*1024 + c0 + cc] : 0.f;
      }
      __syncthreads();
      for (int rr = 0; rr < 32; ++rr) {
        double a0 = sA[ty*4+0][rr], a1 = sA[ty*4+1][rr];
        double a2 = sA[ty*4+2][rr], a3 = sA[ty*4+3][rr];
        double b0 = sB[rr][tx*4+0], b1 = sB[rr][tx*4+1];
        double b2 = sB[rr][tx*4+2], b3 = sB[rr][tx*4+3];
        acc[0][0] += a0*b0; acc[0][1] += a0*b1; acc[0][2] += a0*b2; acc[0][3] += a0*b3;
        acc[1][0] += a1*b0; acc[1][1] += a1*b1; acc[1][2] += a1*b2; acc[1][3] += a1*b3;
        acc[2][0] += a2*b0; acc[2][1] += a2*b1; acc[2][2] += a2*b2; acc[2][3] += a2*b3;
        acc[3][0] += a3*b0; acc[3][1] += a3*b1; acc[3][2] += a3*b2; acc[3][3] += a3*b3;
      }
      __syncthreads();
    }
    #pragma unroll
    for (int i = 0; i < 4; ++i)
      #pragma unroll
      for (int k = 0; k < 4; ++k)
        W[(u64)(ty*4+i)*1024 + c0 + tx*4 + k] = acc[i][k];
  } else {
    double acc[16];
    #pragma unroll
    for (int k = 0; k < 16; ++k) acc[k] = 0.0;
    for (int r0 = rbeg; r0 < 1024; r0 += 32) {
      #pragma unroll
      for (int k = 0; k < 8; ++k) {
        int e = tid + k*256;
        int j = e >> 5, rr = e & 31;
        int r = r0 + rr;
        sA[j][rr] = (r < 1024) ? Vt[(u64)(i0 + j)*1024 + r] : 0.f;
      }
      __syncthreads();
      #pragma unroll
      for (int k = 0; k < 16; ++k) {
        int e = tid + k*256;
        int j1 = e >> 6, j2 = e & 63;
        double s = acc[k];
        for (int rr = 0; rr < 32; ++rr) s += (double)sA[j1][rr]*(double)sA[j2][rr];
        acc[k] = s;
      }
      __syncthreads();
    }
    #pragma unroll
    for (int k = 0; k < 16; ++k) {
      int e = tid + k*256;
      G[(e >> 6)*64 + (e & 63)] = acc[k];
    }
  }
}

// per block: redundantly build T (upper-tri, larft recurrence) in LDS,
// then compute its 64-col tile of TW = T @ W.
__global__ __launch_bounds__(256) void kWyT(const double* __restrict__ G,
    const double* __restrict__ tau, const double* __restrict__ W,
    double* __restrict__ TW, int i0, int nbk) {
  __shared__ double sT[64][65];
  int tid = threadIdx.x;
  for (int e = tid; e < 64*65; e += 256) (&sT[0][0])[e] = 0.0;
  __syncthreads();
  if (tid < nbk) sT[tid][tid] = tau[i0 + tid];
  __syncthreads();
  for (int m = 1; m < nbk; ++m) {
    if (tid < m) {
      double s = 0.0;
      for (int q = tid; q < m; ++q) s += sT[tid][q]*G[q*64 + m];
      sT[tid][m] = -tau[i0 + m]*s;
    }
    __syncthreads();
  }
  int tx = tid & 15, ty = tid >> 4;
  int c0 = blockIdx.x*64;
  #pragma unroll
  for (int i = 0; i < 4; ++i) {
    int j = ty*4 + i;
    #pragma unroll
    for (int k = 0; k < 4; ++k) {
      int c = c0 + tx*4 + k;
      double s = 0.0;
      for (int q = j; q < 64; ++q) s += sT[j][q]*W[(u64)q*1024 + c];
      TW[(u64)j*1024 + c] = s;
    }
  }
}

// Z[r][c] -= sum_j V[r][j] * TW[j][c]   (64-row x 64-col tiles)
__global__ __launch_bounds__(256) void kWyU(const float* __restrict__ Vt,
    const double* __restrict__ TW, float* __restrict__ Qa, int i0, int rbeg) {
  __shared__ float sV[64][65];
  __shared__ double sTW[64][65];
  int tid = threadIdx.x;
  int r0 = rbeg + blockIdx.x*64;
  int c0 = blockIdx.y*64;
  #pragma unroll
  for (int k = 0; k < 16; ++k) {
    int e = tid + k*256;
    int j = e >> 6, rr = e & 63;
    int r = r0 + rr;
    sV[rr][j] = (r < 1024) ? Vt[(u64)(i0 + j)*1024 + r] : 0.f;
  }
  #pragma unroll
  for (int k = 0; k < 16; ++k) {
    int e = tid + k*256;
    int j = e >> 6, cc = e & 63;
    sTW[j][cc] = TW[(u64)j*1024 + c0 + cc];
  }
  __syncthreads();
  int tx = tid & 15, ty = tid >> 4;
  double acc[4][4];
  #pragma unroll
  for (int i = 0; i < 4; ++i)
    #pragma unroll
    for (int k = 0; k < 4; ++k) acc[i][k] = 0.0;
  for (int j = 0; j < 64; ++j) {
    double v0 = sV[ty*4+0][j], v1 = sV[ty*4+1][j];
    double v2 = sV[ty*4+2][j], v3 = sV[ty*4+3][j];
    double t0 = sTW[j][tx*4+0], t1 = sTW[j][tx*4+1];
    double t2 = sTW[j][tx*4+2], t3 = sTW[j][tx*4+3];
    acc[0][0] += v0*t0; acc[0][1] += v0*t1; acc[0][2] += v0*t2; acc[0][3] += v0*t3;
    acc[1][0] += v1*t0; acc[1][1] += v1*t1; acc[1][2] += v1*t2; acc[1][3] += v1*t3;
    acc[2][0] += v2*t0; acc[2][1] += v2*t1; acc[2][2] += v2*t2; acc[2][3] += v2*t3;
    acc[3][0] += v3*t0; acc[3][1] += v3*t1; acc[3][2] += v3*t2; acc[3][3] += v3*t3;
  }
  #pragma unroll
  for (int i = 0; i < 4; ++i) {
    int r = r0 + ty*4 + i;
    if (r < 1024) {
      #pragma unroll
      for (int k = 0; k < 4; ++k) {
        u64 a = (u64)r*1024 + c0 + tx*4 + k;
        Qa[a] = (float)((double)Qa[a] - acc[i][k]);
      }
    }
  }
}

// ================= downstream math =================

// 128x128 tile, 8x8 micro-tile, BK=8, float4 everywhere
template<int TA, int TB>
__global__ __launch_bounds__(256) void gemm_f32(const float* __restrict__ A,
    const float* __restrict__ B, float* __restrict__ C,
    int M, int N, int Kd, int lda, int ldb, int ldc) {
  __shared__ float As[8][132];
  __shared__ float Bs[8][132];
  int tid = threadIdx.x;
  int bi = blockIdx.y*128, bj = blockIdx.x*128;
  int tx = tid & 15, ty = tid >> 4;
  float acc[8][8];
  #pragma unroll
  for (int x = 0; x < 8; ++x)
    #pragma unroll
    for (int y = 0; y < 8; ++y) acc[x][y] = 0.f;
  for (int k0 = 0; k0 < Kd; k0 += 8) {
    if (TA == 0) {
      int row = tid >> 1, kc = (tid & 1)*4;
      float4 v = *(const float4*)&A[(u64)(bi + row)*lda + k0 + kc];
      As[kc+0][row] = v.x; As[kc+1][row] = v.y; As[kc+2][row] = v.z; As[kc+3][row] = v.w;
    } else {
      int kk = tid >> 5, col = (tid & 31)*4;
      float4 v = *(const float4*)&A[(u64)(k0 + kk)*lda + bi + col];
      *(float4*)&As[kk][col] = v;
    }
    if (TB == 0) {
      int kk = tid >> 5, col = (tid & 31)*4;
      float4 v = *(const float4*)&B[(u64)(k0 + kk)*ldb + bj + col];
      *(float4*)&Bs[kk][col] = v;
    } else {
      int row = tid >> 1, kc = (tid & 1)*4;
      float4 v = *(const float4*)&B[(u64)(bj + row)*ldb + k0 + kc];
      Bs[kc+0][row] = v.x; Bs[kc+1][row] = v.y; Bs[kc+2][row] = v.z; Bs[kc+3][row] = v.w;
    }
    __syncthreads();
    #pragma unroll
    for (int kk = 0; kk < 8; ++kk) {
      float a[8], b[8];
      *(float4*)&a[0] = *(float4*)&As[kk][ty*8];
      *(float4*)&a[4] = *(float4*)&As[kk][ty*8 + 4];
      *(float4*)&b[0] = *(float4*)&Bs[kk][tx*8];
      *(float4*)&b[4] = *(float4*)&Bs[kk][tx*8 + 4];
      #pragma unroll
      for (int x = 0; x < 8; ++x)
        #pragma unroll
        for (int y = 0; y < 8; ++y) acc[x][y] += a[x]*b[y];
    }
    __syncthreads();
  }
  #pragma unroll
  for (int x = 0; x < 8; ++x) {
    float* Crow = &C[(u64)(bi + ty*8 + x)*ldc + bj + tx*8];
    *(float4*)&Crow[0] = make_float4(acc[x][0], acc[x][1], acc[x][2], acc[x][3]);
    *(float4*)&Crow[4] = make_float4(acc[x][4], acc[x][5], acc[x][6], acc[x][7]);
  }
}

__global__ void kWc(const float* W, float* Wc) {
  int gid = blockIdx.x*256 + threadIdx.x;
  if (gid >= 2048*1024) return;
  int i = gid >> 10, k = gid & 1023;
  Wc[gid] = W[(u64)i*2048 + k] + W[(u64)i*2048 + 1024 + k];
}

__global__ void kAbsDiag(float* adj) {
  int gid = blockIdx.x*256 + threadIdx.x;
  if (gid >= 2048*2048) return;
  int i = gid >> 11, j = gid & 2047;
  float v = fabsf(adj[gid]);
  adj[gid] = (i == j) ? 1.0f : v;
}

__global__ void kTk(const float* __restrict__ adj, const float* __restrict__ masks,
                    const float* __restrict__ Us, float* __restrict__ t8) {
  int k = blockIdx.y;
  int i = blockIdx.x*16 + (threadIdx.x >> 4);
  int r = threadIdx.x & 15;
  const float* arow = adj + (u64)i*2048;
  const float* mrow = masks + ((u64)k*2048 + i)*2048;
  const float* uk = Us + (u64)k*2048*16 + r;
  float acc = 0.f;
  for (int j = 0; j < 2048; ++j) acc += arow[j]*mrow[j]*uk[(u64)j*16];
  t8[((u64)k*2048 + i)*16 + r] = acc;
}

__global__ void kAlpha(const float* alphas, float* alpha) {
  if (threadIdx.x == 0 && blockIdx.x == 0) {
    float m = alphas[0];
    for (int k = 1; k < 8; ++k) m = fmaxf(m, alphas[k]);
    float e[8]; float s = 0.f;
    for (int k = 0; k < 8; ++k) { e[k] = expf(alphas[k] - m); s += e[k]; }
    for (int k = 0; k < 8; ++k) alpha[k] = e[k]/s;
  }
}

__global__ void kOutAdj(const float* __restrict__ adj, const float* __restrict__ masks,
                        const float* __restrict__ Vs, const float* __restrict__ t8,
                        const float* __restrict__ alpha, float* __restrict__ oadj,
                        float* __restrict__ out0) {
  __shared__ float tS[8][16][16];
  __shared__ float vS[8][16][16];
  int j0 = blockIdx.x*16, i0 = blockIdx.y*16;
  int tid = threadIdx.x;
  for (int idx = tid; idx < 2048; idx += 256) {
    int k = idx >> 8, rem = idx & 255, row = rem >> 4, r = rem & 15;
    tS[k][row][r] = t8[((u64)k*2048 + i0 + row)*16 + r];
    vS[k][row][r] = Vs[((u64)k*2048 + j0 + row)*16 + r];
  }
  __syncthreads();
  int ii = tid >> 4, jj = tid & 15;
  int i = i0 + ii, j = j0 + jj;
  float corr = 0.f;
  for (int k = 0; k < 8; ++k) {
    float m = masks[((u64)k*2048 + i)*2048 + j];
    float dv = 0.f;
    #pragma unroll
    for (int r = 0; r < 16; ++r) dv += tS[k][ii][r]*vS[k][jj][r];
    corr += alpha[k]*m*dv;
  }
  float val = adj[(u64)i*2048 + j] + corr;
  oadj[(u64)i*2048 + j] = val;
  out0[(u64)i*2048 + j] = val;
}

__global__ void kFinal(const float* __restrict__ C, float* __restrict__ out1) {
  int gid = blockIdx.x*256 + threadIdx.x;
  if (gid >= 2048*2048) return;
  int i = gid >> 11, j = gid & 2047;
  float v;
  if (i == j) v = 1.0f;
  else v = 0.5f*(C[gid] + C[(u64)j*2048 + i]);
  out1[gid] = fabsf(v);
}

// ================= host =================

extern "C" void kernel_launch(void* const* d_in, const int* in_sizes, int n_in,
                              void* d_out, int out_size, void* d_ws, size_t ws_size,
                              hipStream_t stream) {
  const float* A      = (const float*)d_in[0];
  const float* X      = (const float*)d_in[1];
  const float* W      = (const float*)d_in[2];
  const float* Us     = (const float*)d_in[3];
  const float* Vs     = (const float*)d_in[4];
  const float* alphas = (const float*)d_in[5];
  const float* masks  = (const float*)d_in[6];

  char* ws = (char*)d_ws;
  double* A64  = (double*)(ws + OFF_A64);
  float*  Vt   = (float*) (ws + OFF_VT);
  double* tau  = (double*)(ws + OFF_TAU);
  double* d64  = (double*)(ws + OFF_D64);
  double* e64  = (double*)(ws + OFF_E64);
  double* diagP = (double*)(ws + OFF_XA);
  unsigned* flags = (unsigned*)(ws + OFF_XB);
  double* y1a  = (double*)(ws + OFF_Y1A);
  double* y1b  = (double*)(ws + OFF_Y1B);
  double* y2a  = (double*)(ws + OFF_Y2A);
  double* y2b  = (double*)(ws + OFF_Y2B);
  double* SCDB = (double*)(ws + OFF_SCDB);
  int*    SCIB = (int*)   (ws + OFF_SCIB);
  int*    KNB  = (int*)   (ws + OFF_KNB);
  double* KNDB = (double*)(ws + OFF_KNDB);
  double* WYW  = (double*)(ws + OFF_WYW);
  double* WYTW = (double*)(ws + OFF_WYTW);
  double* WYG  = (double*)(ws + OFF_WYG);
  float*  ALPH = (float*) (ws + OFF_ALPHA);
  float*  Qa   = (float*) (ws + OFF_QA);
  float*  Qb   = (float*) (ws + OFF_QB);
  float*  Shat = (float*) (ws + OFF_SHAT);
  float*  Wc   = (float*) (ws + OFF_WC);
  float*  M1   = (float*) (ws + OFF_M1);
  float*  T8   = (float*) (ws + OFF_T8);
  float*  ADJ  = (float*) (ws + OFF_ADJ);
  float*  OADJ = (float*) (ws + OFF_OADJ);
  float*  CB   = (float*) (ws + OFF_CBUF);

  float* out0 = (float*)d_out;                 // reference outputs are float32
  float* out1 = out0 + (u64)2048*2048;

  // --- tridiagonalization: 1 persistent launch (64 blocks), flag barrier ---
  hipMemsetAsync(ws + OFF_XB, 0, 4096, stream);    // zero 64 padded barrier flags
  kCopyA<<<4096, 256, 0, stream>>>(A, A64);
  {
    void* kargs[] = { (void*)&A64, (void*)&y1a, (void*)&y1b, (void*)&y2a, (void*)&y2b,
                      (void*)&diagP, (void*)&flags,
                      (void*)&tau, (void*)&e64, (void*)&d64, (void*)&Vt };
    hipLaunchCooperativeKernel((void*)kTriDiag, dim3(TD_NBLK), dim3(1024), kargs, 0, stream);
  }

  // --- D&C: leaves, batched merges (cuts folded into kTriDiag tail) ---
  hipMemsetAsync(Qa, 0, (size_t)4*MBYTE, stream);
  kLeaf<<<64, 64, 0, stream>>>(d64, e64, Qa);

  for (int lvl = 0; lvl < 6; ++lvl) {
    int bs = 16 << lvl;
    int n = 2*bs;
    int cnt = 1024/n;
    kDeflateB<<<cnt, 1024, 0, stream>>>(Qa, d64, e64, SCDB, SCIB, KNB, KNDB, bs);
    kSecularB<<<dim3((n + 3)/4, cnt), 256, 0, stream>>>(SCDB, KNB, KNDB);
    kZhatB<<<dim3((n + 63)/64, cnt), 64, 0, stream>>>(SCDB, KNB);
    kSortPermB<<<cnt, 1024, 0, stream>>>(SCDB, SCIB, KNB, d64, bs);
    kSvecNormB<<<dim3(n, cnt), 256, 0, stream>>>(Shat, SCDB, KNB, bs);
    kGatherB<<<dim3((n*n + 255)/256, cnt), 256, 0, stream>>>(Qa, Qb, SCIB, KNB, bs);
    kGemmMergeB<<<dim3(n/16, n/16, cnt), dim3(16, 16), 0, stream>>>(Qb, Shat, Qa, SCIB, KNB, bs);
    kScatterDeflB<<<dim3((n*n + 255)/256, cnt), 256, 0, stream>>>(Qb, Qa, SCIB, KNB, bs);
  }

  // --- back-transform: blocked compact-WY, Qa = U (eigenvectors of A) ---
  kVtZero<<<4096, 256, 0, stream>>>(Vt);
  for (int i0 = 960; i0 >= 0; i0 -= 64) {
    int nbk = (i0 == 960) ? 63 : 64;       // reflectors 0..1022 only
    int rbeg = i0 + 1;
    int L = 1024 - rbeg;
    kWyW<<<17, 256, 0, stream>>>(Vt, Qa, WYW, WYG, i0, rbeg);
    kWyT<<<16, 256, 0, stream>>>(WYG, tau, WYW, WYTW, i0, nbk);
    kWyU<<<dim3((L + 63)/64, 16), 256, 0, stream>>>(Vt, WYTW, Qa, i0, rbeg);
  }

  // --- downstream pipeline ---
  kWc<<<8192, 256, 0, stream>>>(W, Wc);
  // M1 = U^T @ X  (1024 x 2048)
  gemm_f32<1,0><<<dim3(16, 8), 256, 0, stream>>>(Qa, X, M1, 1024, 2048, 1024, 1024, 2048, 2048);
  // f_d = Wc @ M1 (2048 x 2048) -> ADJ
  gemm_f32<0,0><<<dim3(16, 16), 256, 0, stream>>>(Wc, M1, ADJ, 2048, 2048, 1024, 1024, 2048, 2048);
  kAbsDiag<<<16384, 256, 0, stream>>>(ADJ);
  kTk<<<dim3(128, 8), 256, 0, stream>>>(ADJ, masks, Us, T8);
  kAlpha<<<1, 64, 0, stream>>>(alphas, ALPH);
  kOutAdj<<<dim3(128, 128), 256, 0, stream>>>(ADJ, masks, Vs, T8, ALPH, OADJ, out0);
  // C = out_adj @ out_adj^T
  gemm_f32<0,1><<<dim3(16, 16), 256, 0, stream>>>(OADJ, OADJ, CB, 2048, 2048, 2048, 2048, 2048, 2048);
  kFinal<<<16384, 256, 0, stream>>>(CB, out1);
}